// Round 10
// baseline (504.993 us; speedup 1.0000x reference)
//
#include <hip/hip_runtime.h>

#define M1 98304
#define RDIM 512
#define FDIM 2048
#define SDIM 96
#define BM 96
#define BK 64

typedef __attribute__((ext_vector_type(8))) __bf16 bf16x8;
typedef __attribute__((ext_vector_type(4))) float f32x4;

#define WAITV6 asm volatile("s_waitcnt vmcnt(6)" ::: "memory")
#define WAITV3 asm volatile("s_waitcnt vmcnt(3)" ::: "memory")
#define WAITV0 asm volatile("s_waitcnt vmcnt(0)" ::: "memory")
#define WAITL0 asm volatile("s_waitcnt lgkmcnt(0)" ::: "memory")
#define SBAR   __builtin_amdgcn_s_barrier()
#define SCHED0 __builtin_amdgcn_sched_barrier(0)

__device__ __forceinline__ float bf2f(unsigned short u){
  union { unsigned int i; float f; } v; v.i = ((unsigned int)u) << 16; return v.f;
}
__device__ __forceinline__ unsigned short f2bf(float f){
  union { float f; unsigned int i; } v; v.f = f;
  unsigned int r = v.i + 0x7FFFu + ((v.i >> 16) & 1u);
  return (unsigned short)(r >> 16);
}
__device__ __forceinline__ unsigned short f2bfn(float f){
  __bf16 b = (__bf16)f;
  return __builtin_bit_cast(unsigned short, b);
}
__device__ __forceinline__ float fast_tanh(float x){
  float e = __expf(2.f * x);
  return 1.f - 2.f / (e + 1.f);
}
__device__ __forceinline__ void gld_lds16(const void* g, void* l){
  __builtin_amdgcn_global_load_lds((const __attribute__((address_space(1))) void*)g,
                                   (__attribute__((address_space(3))) void*)l, 16, 0, 0);
}
__device__ __forceinline__ f32x4 mfma16(bf16x8 a, bf16x8 b, f32x4 c){
  return __builtin_amdgcn_mfma_f32_16x16x32_bf16(a, b, c, 0, 0, 0);
}

// ---------------- convert / split kernels ----------------
__device__ __forceinline__ void cat_store_a(const float* __restrict__ src,
                                            unsigned short* __restrict__ dst, int idx){
  float x = src[idx];
  int r = idx >> 9, c = idx & 511;
  unsigned short hi = f2bf(x);
  unsigned short lo = f2bf(x - bf2f(hi));
  unsigned short* p = dst + (long)r * 1536 + c;
  p[0] = hi; p[512] = lo; p[1024] = hi;
}
__device__ __forceinline__ void cat_store_w(const float* __restrict__ src,
                                            unsigned short* __restrict__ dst, int idx){
  float x = src[idx];
  int r = idx >> 9, c = idx & 511;
  unsigned short hi = f2bf(x);
  unsigned short lo = f2bf(x - bf2f(hi));
  unsigned short* p = dst + (long)r * 1536 + c;
  p[0] = hi; p[512] = hi; p[1024] = lo;
}

__global__ void k_convert(const float* W_ae, const float* W_c, const float* W_s,
                          const float* W_h, const float* h, const float* sent,
                          unsigned short* W_ae_bf, unsigned short* W_c_bf,
                          unsigned short* W_s_cat, unsigned short* W_h_cat,
                          unsigned short* h_cat, unsigned short* s_cat){
  const int stride = 1024 * 256;
  int i0 = blockIdx.x * 256 + threadIdx.x;
  switch (blockIdx.y) {
    case 0: for (int i = i0; i < 512*2048; i += stride) W_ae_bf[i] = f2bf(W_ae[i]); break;
    case 1: for (int i = i0; i < 512*512;  i += stride) W_c_bf[i]  = f2bf(W_c[i]);  break;
    case 2: for (int i = i0; i < 512*512;  i += stride) cat_store_w(W_s, W_s_cat, i); break;
    case 3: for (int i = i0; i < 512*512;  i += stride) cat_store_w(W_h, W_h_cat, i); break;
    case 4: for (int i = i0; i < 1024*512; i += stride) cat_store_a(h, h_cat, i); break;
    case 5: for (int i = i0; i < 1024*512; i += stride) cat_store_a(sent, s_cat, i); break;
  }
}

// ========= FUSED: gemm1 + gemm2 + softmax + cHat + att2h (full tail) ========
__global__ __launch_bounds__(512) void k_fused(
    const float* __restrict__ Af, const unsigned short* __restrict__ Wae,
    const float* __restrict__ b_ae,
    const unsigned short* __restrict__ Wcg, const float* __restrict__ b_c,
    const float* __restrict__ h_e, const float* __restrict__ W_al,
    const float* __restrict__ sent_e, const float* __restrict__ sent,
    const float* __restrict__ hvec,
    const float* __restrict__ W_o, const float* __restrict__ b_o,
    float* __restrict__ out){
  __shared__ __align__(16) char smem[155648];
  unsigned short* As   = (unsigned short*)smem;          // ph1 [2][96*64]
  unsigned short* Bs   = (unsigned short*)(smem + 24576);// ph1 [2][512*64]
  unsigned short* attL = (unsigned short*)smem;          // ph2 [96*512]
  unsigned short* Wcs  = (unsigned short*)(smem + 98304);// ph2 [512*32]
  float* atten_s = (float*)(smem + 98304);               // tail [512] (over Wcs)
  float* part = (float*)(smem + 131072);
  float* lg   = (float*)(smem + 131072 + 1536);
  float* alp  = (float*)(smem + 131072 + 1536 + 512);
  float* ssum = (float*)(smem + 131072 + 1536 + 1024);

  const int tid = threadIdx.x;
  const int w = tid >> 6, l = tid & 63;
  const int wm = w >> 2, wn = w & 3;
  const int b = blockIdx.x;
  const long m0 = (long)b * BM;
  const int g = l >> 4, r15 = l & 15;
  const int rs = r15 & 7;

  f32x4 acc[3][8];
#pragma unroll
  for (int i = 0; i < 3; ++i)
#pragma unroll
    for (int j = 0; j < 8; ++j) acc[i][j] = f32x4{0.f,0.f,0.f,0.f};

  // ---------------- phase 1: counted-vmcnt pipeline (R8-verbatim) -----------
  {
    const int brow_in = l >> 3;
    const int bswz = (l & 7) ^ brow_in;
    const unsigned short* bbase = Wae + (long)(w*64 + brow_in) * FDIM + bswz*8;
    int aswz[3];
    const float* abase[3];
#pragma unroll
    for (int s = 0; s < 3; ++s) {
      int c = tid + s*512;
      int arow = c >> 4, akq = c & 15;
      abase[s] = Af + (m0 + arow)*FDIM + akq*4;
      aswz[s] = arow*BK + ((akq ^ ((arow&7)<<1))<<2);
    }
    const int NT = FDIM / BK;  // 32
    float4 d0,d1,d2, e0,e1,e2;
    float4 f0 = {0,0,0,0}, f1 = {0,0,0,0}, f2 = {0,0,0,0};

    {
      float4 c0 = *reinterpret_cast<const float4*>(abase[0]);
      float4 c1 = *reinterpret_cast<const float4*>(abase[1]);
      float4 c2 = *reinterpret_cast<const float4*>(abase[2]);
      SCHED0;
#pragma unroll
      for (int q = 0; q < 8; ++q)
        gld_lds16(bbase + (long)q*8*FDIM, Bs + (w*8+q)*512);
      SCHED0;
      d0 = *reinterpret_cast<const float4*>(abase[0] + BK);
      d1 = *reinterpret_cast<const float4*>(abase[1] + BK);
      d2 = *reinterpret_cast<const float4*>(abase[2] + BK);
      e0 = *reinterpret_cast<const float4*>(abase[0] + 2*BK);
      e1 = *reinterpret_cast<const float4*>(abase[1] + 2*BK);
      e2 = *reinterpret_cast<const float4*>(abase[2] + 2*BK);
      SCHED0;
      ushort4 p0; p0.x=f2bfn(c0.x); p0.y=f2bfn(c0.y); p0.z=f2bfn(c0.z); p0.w=f2bfn(c0.w);
      ushort4 p1; p1.x=f2bfn(c1.x); p1.y=f2bfn(c1.y); p1.z=f2bfn(c1.z); p1.w=f2bfn(c1.w);
      ushort4 p2; p2.x=f2bfn(c2.x); p2.y=f2bfn(c2.y); p2.z=f2bfn(c2.z); p2.w=f2bfn(c2.w);
      *reinterpret_cast<ushort4*>(&As[aswz[0]]) = p0;
      *reinterpret_cast<ushort4*>(&As[aswz[1]]) = p1;
      *reinterpret_cast<ushort4*>(&As[aswz[2]]) = p2;
      WAITV6; WAITL0; SCHED0; SBAR; SCHED0;
    }

    int cb = 0;
    for (int kt = 0; kt < NT; ++kt) {
      const int nb = cb ^ 1;
      if (kt + 1 < NT) {
        const long kof = (long)(kt+1) * BK;
#pragma unroll
        for (int q = 0; q < 8; ++q)
          gld_lds16(bbase + (long)q*8*FDIM + kof, Bs + nb*32768 + (w*8+q)*512);
      }
      SCHED0;
      if (kt + 3 < NT) {
        const long kof = (long)(kt+3) * BK;
        f0 = *reinterpret_cast<const float4*>(abase[0] + kof);
        f1 = *reinterpret_cast<const float4*>(abase[1] + kof);
        f2 = *reinterpret_cast<const float4*>(abase[2] + kof);
      }
      SCHED0;
#pragma unroll
      for (int hh = 0; hh < 2; ++hh) {
        const int ko = ((g + 4*hh) ^ rs) << 3;
        bf16x8 afr[3], bfr[8];
#pragma unroll
        for (int i = 0; i < 3; ++i)
          afr[i] = *reinterpret_cast<const bf16x8*>(&As[cb*6144 + (wm*48 + i*16 + r15)*BK + ko]);
#pragma unroll
        for (int j = 0; j < 8; ++j)
          bfr[j] = *reinterpret_cast<const bf16x8*>(&Bs[cb*32768 + (wn*128 + j*16 + r15)*BK + ko]);
        __builtin_amdgcn_s_setprio(1);
#pragma unroll
        for (int i = 0; i < 3; ++i)
#pragma unroll
          for (int j = 0; j < 8; ++j)
            acc[i][j] = mfma16(afr[i], bfr[j], acc[i][j]);
        __builtin_amdgcn_s_setprio(0);
      }
      if (kt + 1 < NT) {
        ushort4 p0; p0.x=f2bfn(d0.x); p0.y=f2bfn(d0.y); p0.z=f2bfn(d0.z); p0.w=f2bfn(d0.w);
        ushort4 p1; p1.x=f2bfn(d1.x); p1.y=f2bfn(d1.y); p1.z=f2bfn(d1.z); p1.w=f2bfn(d1.w);
        ushort4 p2; p2.x=f2bfn(d2.x); p2.y=f2bfn(d2.y); p2.z=f2bfn(d2.z); p2.w=f2bfn(d2.w);
        *reinterpret_cast<ushort4*>(&As[nb*6144 + aswz[0]]) = p0;
        *reinterpret_cast<ushort4*>(&As[nb*6144 + aswz[1]]) = p1;
        *reinterpret_cast<ushort4*>(&As[nb*6144 + aswz[2]]) = p2;
        d0=e0; d1=e1; d2=e2; e0=f0; e1=f1; e2=f2;
        if (kt + 3 < NT) { WAITV3; } else { WAITV0; }
        WAITL0; SCHED0; SBAR; SCHED0;
        cb = nb;
      }
    }
  }
  __syncthreads();
  // phase-1 epilogue: relu(acc+bias) -> attL (bf16, grp^(row&7) swizzle)
  {
    float bb[8];
#pragma unroll
    for (int j = 0; j < 8; ++j) bb[j] = b_ae[wn*128 + j*16 + r15];
#pragma unroll
    for (int i = 0; i < 3; ++i)
#pragma unroll
      for (int r = 0; r < 4; ++r) {
        int row = wm*48 + i*16 + g*4 + r;
        int rs8 = row & 7;
#pragma unroll
        for (int j = 0; j < 8; ++j) {
          int col = wn*128 + j*16 + r15;
          float x = acc[i][j][r] + bb[j];
          x = x > 0.f ? x : 0.f;
          attL[row*512 + (((col>>3) ^ rs8)<<3) + (col&7)] = f2bfn(x);
        }
      }
  }
  __syncthreads();

  // ------- phase 2: att @ Wc^T, W_c reg-staged (T14), lgkm-only barriers ----
#pragma unroll
  for (int i = 0; i < 3; ++i)
#pragma unroll
    for (int j = 0; j < 8; ++j) acc[i][j] = f32x4{0.f,0.f,0.f,0.f};
  {
    const int crow = l >> 2;
    const int bsl2 = (l & 3) ^ ((l >> 3) & 3);
    const int rs2 = (r15 >> 1) & 3;
    uint4 rr0, rr1, rr2, rr3;
    rr0 = *reinterpret_cast<const uint4*>(Wcg + (long)(w*64 + 0*16 + crow)*RDIM + bsl2*8);
    rr1 = *reinterpret_cast<const uint4*>(Wcg + (long)(w*64 + 1*16 + crow)*RDIM + bsl2*8);
    rr2 = *reinterpret_cast<const uint4*>(Wcg + (long)(w*64 + 2*16 + crow)*RDIM + bsl2*8);
    rr3 = *reinterpret_cast<const uint4*>(Wcg + (long)(w*64 + 3*16 + crow)*RDIM + bsl2*8);
    for (int kt = 0; kt < 16; ++kt) {
      *reinterpret_cast<uint4*>(&Wcs[w*2048 + 0*512 + l*8]) = rr0;
      *reinterpret_cast<uint4*>(&Wcs[w*2048 + 1*512 + l*8]) = rr1;
      *reinterpret_cast<uint4*>(&Wcs[w*2048 + 2*512 + l*8]) = rr2;
      *reinterpret_cast<uint4*>(&Wcs[w*2048 + 3*512 + l*8]) = rr3;
      if (kt < 15) {
        const int k0 = (kt+1)*32;
        rr0 = *reinterpret_cast<const uint4*>(Wcg + (long)(w*64 + 0*16 + crow)*RDIM + k0 + bsl2*8);
        rr1 = *reinterpret_cast<const uint4*>(Wcg + (long)(w*64 + 1*16 + crow)*RDIM + k0 + bsl2*8);
        rr2 = *reinterpret_cast<const uint4*>(Wcg + (long)(w*64 + 2*16 + crow)*RDIM + k0 + bsl2*8);
        rr3 = *reinterpret_cast<const uint4*>(Wcg + (long)(w*64 + 3*16 + crow)*RDIM + k0 + bsl2*8);
      }
      WAITL0; SCHED0; SBAR; SCHED0;
      bf16x8 afr[3], bfr[8];
#pragma unroll
      for (int i = 0; i < 3; ++i) {
        int ra = wm*48 + i*16 + r15;
        int grp = (kt<<2) + g;
        afr[i] = *reinterpret_cast<const bf16x8*>(&attL[ra*512 + ((grp ^ rs)<<3)]);
      }
#pragma unroll
      for (int j = 0; j < 8; ++j)
        bfr[j] = *reinterpret_cast<const bf16x8*>(&Wcs[(wn*128 + j*16 + r15)*32 + ((g ^ rs2)<<3)]);
      __builtin_amdgcn_s_setprio(1);
#pragma unroll
      for (int i = 0; i < 3; ++i)
#pragma unroll
        for (int j = 0; j < 8; ++j)
          acc[i][j] = mfma16(afr[i], bfr[j], acc[i][j]);
      __builtin_amdgcn_s_setprio(0);
      WAITL0; SCHED0; SBAR; SCHED0;
    }
  }
  // logits epilogue
  {
    const float* hrow = h_e + (long)b * RDIM;
    float bb2[8], wa[8], he[8];
#pragma unroll
    for (int j = 0; j < 8; ++j) {
      int n = wn*128 + j*16 + r15;
      bb2[j] = b_c[n]; wa[j] = W_al[n]; he[j] = hrow[n];
    }
#pragma unroll
    for (int i = 0; i < 3; ++i)
#pragma unroll
      for (int r = 0; r < 4; ++r) {
        int lrow = wm*48 + i*16 + g*4 + r;
        float s = 0.f;
#pragma unroll
        for (int j = 0; j < 8; ++j) {
          float x = acc[i][j][r] + bb2[j] + he[j];
          s += fast_tanh(x) * wa[j];
        }
        s += __shfl_xor(s, 1); s += __shfl_xor(s, 2);
        s += __shfl_xor(s, 4); s += __shfl_xor(s, 8);
        if (r15 == 0) part[lrow*4 + wn] = s;
      }
  }
  __syncthreads();
  if (tid < 96)
    lg[1+tid] = part[tid*4+0] + part[tid*4+1] + part[tid*4+2] + part[tid*4+3];
  if (tid < 64) {
    float s = 0.f;
    for (int a = tid; a < 512; a += 64)
      s += fast_tanh(sent_e[(long)b*512 + a] + h_e[(long)b*512 + a]) * W_al[a];
    s += __shfl_xor(s, 1); s += __shfl_xor(s, 2); s += __shfl_xor(s, 4);
    s += __shfl_xor(s, 8); s += __shfl_xor(s, 16); s += __shfl_xor(s, 32);
    if (tid == 0) lg[0] = s;
  }
  __syncthreads();
  if (tid < 64) {
    float m = -1e30f;
    for (int i = tid; i < 97; i += 64) m = fmaxf(m, lg[i]);
#pragma unroll
    for (int k = 1; k < 64; k <<= 1) m = fmaxf(m, __shfl_xor(m, k));
    float ss = 0.f;
    for (int i = tid; i < 97; i += 64) { float e = __expf(lg[i] - m); alp[i] = e; ss += e; }
#pragma unroll
    for (int k = 1; k < 64; k <<= 1) ss += __shfl_xor(ss, k);
    if (tid == 0) ssum[0] = ss;
  }
  __syncthreads();
  if (tid < 97) alp[tid] *= (1.f / ssum[0]);
  __syncthreads();
  // cHat + atten_out -> LDS (f32)
  {
    const int col = tid;
    const int cg = col >> 3, ch = col & 7;
    float accv = alp[0] * sent[(long)b*512 + col];
#pragma unroll 4
    for (int s = 0; s < SDIM; ++s)
      accv += alp[s+1] * bf2f(attL[s*512 + ((cg ^ (s&7))<<3) + ch]);
    atten_s[col] = accv + hvec[(long)b*512 + col];
  }
  __syncthreads();
  // att2h tail: out[b][t] = tanh(atten . W_o[t][:] + b_o[t])  (f32 VALU)
  {
    const float* wrow = W_o + (long)tid * 512;
    float s = 0.f;
#pragma unroll 4
    for (int a = 0; a < 512; a += 4) {
      float4 w4 = *reinterpret_cast<const float4*>(wrow + a);
      float4 a4 = *reinterpret_cast<const float4*>(atten_s + a);
      s += a4.x*w4.x + a4.y*w4.y + a4.z*w4.z + a4.w*w4.w;
    }
    out[(long)b*512 + tid] = fast_tanh(s + b_o[tid]);
  }
}

// ---------------- small GEMM body (K=1536 hi/lo-cat), dbuf ------------------
__device__ __forceinline__ void small_gemm_body(
    const unsigned short* __restrict__ Abf, const unsigned short* __restrict__ Wb,
    const float* __restrict__ bias, float* __restrict__ Cout, int bx,
    unsigned short* As, unsigned short* Bs){
  const int tid = threadIdx.x;
  const int w = tid >> 6, l = tid & 63;
  const int wm = w >> 1, wn = w & 1;
  const int m0 = (bx >> 3) * 64, n0 = (bx & 7) * 64;
  const int K = 1536;
  f32x4 acc[2][2];
#pragma unroll
  for (int i = 0; i < 2; ++i)
#pragma unroll
    for (int j = 0; j < 2; ++j) acc[i][j] = f32x4{0.f,0.f,0.f,0.f};

  const int crow = l >> 2;
  const int bsl = (l & 3) ^ ((l >> 3) & 3);
  const unsigned short* arow_p = Abf + (long)(m0 + w*16 + crow)*K + bsl*8;
  const unsigned short* brow_p = Wb  + (long)(n0 + w*16 + crow)*K + bsl*8;

  gld_lds16(arow_p, As + w*512);
  gld_lds16(brow_p, Bs + w*512);
  __syncthreads();
  int cb = 0;
  for (int kt = 0; kt < 48; ++kt) {
    const int nb = cb ^ 1;
    if (kt + 1 < 48) {
      const int k0 = (kt+1) * 32;
      gld_lds16(arow_p + k0, As + nb*2048 + w*512);
      gld_lds16(brow_p + k0, Bs + nb*2048 + w*512);
    }
    bf16x8 afr[2], bfr[2];
    const int g = l >> 4, r15 = l & 15;
    const int rs2 = (r15 >> 1) & 3;
#pragma unroll
    for (int i = 0; i < 2; ++i)
      afr[i] = *reinterpret_cast<const bf16x8*>(As + cb*2048 + (wm*32 + i*16 + r15)*32 + ((g ^ rs2)*8));
#pragma unroll
    for (int j = 0; j < 2; ++j)
      bfr[j] = *reinterpret_cast<const bf16x8*>(Bs + cb*2048 + (wn*32 + j*16 + r15)*32 + ((g ^ rs2)*8));
#pragma unroll
    for (int i = 0; i < 2; ++i)
#pragma unroll
      for (int j = 0; j < 2; ++j)
        acc[i][j] = mfma16(afr[i], bfr[j], acc[i][j]);
    if (kt + 1 < 48) { __syncthreads(); cb = nb; }
  }
  const int r15 = l & 15, g = l >> 4;
#pragma unroll
  for (int i = 0; i < 2; ++i)
#pragma unroll
    for (int r = 0; r < 4; ++r) {
      int m = m0 + wm*32 + i*16 + g*4 + r;
#pragma unroll
      for (int j = 0; j < 2; ++j) {
        int n = n0 + wn*32 + j*16 + r15;
        Cout[(long)m * 512 + n] = acc[i][j][r] + bias[n];
      }
    }
}

__global__ __launch_bounds__(256) void k_embed2(
    const unsigned short* __restrict__ h_cat, const unsigned short* __restrict__ W_h_cat,
    const float* __restrict__ b_h, float* __restrict__ h_e,
    const unsigned short* __restrict__ s_cat, const unsigned short* __restrict__ W_s_cat,
    const float* __restrict__ b_s, float* __restrict__ sent_e){
  __shared__ __align__(16) unsigned short As[2*64*32];
  __shared__ __align__(16) unsigned short Bs[2*64*32];
  if (blockIdx.y == 0) small_gemm_body(h_cat, W_h_cat, b_h, h_e, blockIdx.x, As, Bs);
  else                 small_gemm_body(s_cat, W_s_cat, b_s, sent_e, blockIdx.x, As, Bs);
}

extern "C" void kernel_launch(void* const* d_in, const int* in_sizes, int n_in,
                              void* d_out, int out_size, void* d_ws, size_t ws_size,
                              hipStream_t stream){
  (void)in_sizes; (void)n_in; (void)out_size; (void)ws_size;
  const float* h    = (const float*)d_in[0];
  const float* sent = (const float*)d_in[1];
  const float* feats= (const float*)d_in[2];
  const float* W_ae = (const float*)d_in[3];
  const float* b_ae = (const float*)d_in[4];
  const float* W_c  = (const float*)d_in[5];
  const float* b_c  = (const float*)d_in[6];
  const float* W_s  = (const float*)d_in[7];
  const float* b_s  = (const float*)d_in[8];
  const float* W_h  = (const float*)d_in[9];
  const float* b_h  = (const float*)d_in[10];
  const float* W_al = (const float*)d_in[11];
  const float* W_o  = (const float*)d_in[13];
  const float* b_o  = (const float*)d_in[14];
  float* out = (float*)d_out;

  char* p = (char*)d_ws;
  unsigned short* W_ae_bf = (unsigned short*)p; p += (size_t)512*2048*2;
  unsigned short* W_c_bf  = (unsigned short*)p; p += (size_t)512*512*2;
  unsigned short* W_s_cat = (unsigned short*)p; p += (size_t)512*1536*2;
  unsigned short* W_h_cat = (unsigned short*)p; p += (size_t)512*1536*2;
  unsigned short* h_cat   = (unsigned short*)p; p += (size_t)1024*1536*2;
  unsigned short* s_cat   = (unsigned short*)p; p += (size_t)1024*1536*2;
  float* h_e    = (float*)p; p += (size_t)1024*512*4;
  float* sent_e = (float*)p; p += (size_t)1024*512*4;

  k_convert<<<dim3(1024,6), 256, 0, stream>>>(W_ae, W_c, W_s, W_h, h, sent,
        W_ae_bf, W_c_bf, W_s_cat, W_h_cat, h_cat, s_cat);
  k_embed2<<<dim3(128,2), 256, 0, stream>>>(h_cat, W_h_cat, b_h, h_e,
                                            s_cat, W_s_cat, b_s, sent_e);
  k_fused<<<1024, 512, 0, stream>>>(feats, W_ae_bf, b_ae, W_c_bf, b_c,
                                    h_e, W_al, sent_e, sent, h, W_o, b_o, out);
}

// Round 11
// 418.891 us; speedup vs baseline: 1.2055x; 1.2055x over previous
//
#include <hip/hip_runtime.h>

#define M1 98304
#define RDIM 512
#define FDIM 2048
#define SDIM 96
#define BM 96
#define BK 64

typedef __attribute__((ext_vector_type(8))) __bf16 bf16x8;
typedef __attribute__((ext_vector_type(4))) float f32x4;

#define WAITV6 asm volatile("s_waitcnt vmcnt(6)" ::: "memory")
#define WAITV3 asm volatile("s_waitcnt vmcnt(3)" ::: "memory")
#define WAITV0 asm volatile("s_waitcnt vmcnt(0)" ::: "memory")
#define WAITL0 asm volatile("s_waitcnt lgkmcnt(0)" ::: "memory")
#define SBAR   __builtin_amdgcn_s_barrier()
#define SCHED0 __builtin_amdgcn_sched_barrier(0)

__device__ __forceinline__ float bf2f(unsigned short u){
  union { unsigned int i; float f; } v; v.i = ((unsigned int)u) << 16; return v.f;
}
__device__ __forceinline__ unsigned short f2bf(float f){
  union { float f; unsigned int i; } v; v.f = f;
  unsigned int r = v.i + 0x7FFFu + ((v.i >> 16) & 1u);
  return (unsigned short)(r >> 16);
}
__device__ __forceinline__ unsigned short f2bfn(float f){
  __bf16 b = (__bf16)f;
  return __builtin_bit_cast(unsigned short, b);
}
__device__ __forceinline__ float fast_tanh(float x){
  float e = __expf(2.f * x);
  return 1.f - 2.f / (e + 1.f);
}
__device__ __forceinline__ void gld_lds16(const void* g, void* l){
  __builtin_amdgcn_global_load_lds((const __attribute__((address_space(1))) void*)g,
                                   (__attribute__((address_space(3))) void*)l, 16, 0, 0);
}
__device__ __forceinline__ f32x4 mfma16(bf16x8 a, bf16x8 b, f32x4 c){
  return __builtin_amdgcn_mfma_f32_16x16x32_bf16(a, b, c, 0, 0, 0);
}

// ---------------- convert / split kernels ----------------
__device__ __forceinline__ void cat_store_a(const float* __restrict__ src,
                                            unsigned short* __restrict__ dst, int idx){
  float x = src[idx];
  int r = idx >> 9, c = idx & 511;
  unsigned short hi = f2bf(x);
  unsigned short lo = f2bf(x - bf2f(hi));
  unsigned short* p = dst + (long)r * 1536 + c;
  p[0] = hi; p[512] = lo; p[1024] = hi;
}
__device__ __forceinline__ void cat_store_w(const float* __restrict__ src,
                                            unsigned short* __restrict__ dst, int idx){
  float x = src[idx];
  int r = idx >> 9, c = idx & 511;
  unsigned short hi = f2bf(x);
  unsigned short lo = f2bf(x - bf2f(hi));
  unsigned short* p = dst + (long)r * 1536 + c;
  p[0] = hi; p[512] = hi; p[1024] = lo;
}

__global__ void k_convert(const float* W_ae, const float* W_c, const float* W_s,
                          const float* W_h, const float* W_o,
                          const float* h, const float* sent,
                          unsigned short* W_ae_bf, unsigned short* W_c_bf,
                          unsigned short* W_s_cat, unsigned short* W_h_cat,
                          unsigned short* W_o_cat, unsigned short* h_cat,
                          unsigned short* s_cat){
  const int stride = 1024 * 256;
  int i0 = blockIdx.x * 256 + threadIdx.x;
  switch (blockIdx.y) {
    case 0: for (int i = i0; i < 512*2048; i += stride) W_ae_bf[i] = f2bf(W_ae[i]); break;
    case 1: for (int i = i0; i < 512*512;  i += stride) W_c_bf[i]  = f2bf(W_c[i]);  break;
    case 2: for (int i = i0; i < 512*512;  i += stride) cat_store_w(W_s, W_s_cat, i); break;
    case 3: for (int i = i0; i < 512*512;  i += stride) cat_store_w(W_h, W_h_cat, i); break;
    case 4: for (int i = i0; i < 512*512;  i += stride) cat_store_w(W_o, W_o_cat, i); break;
    case 5: for (int i = i0; i < 1024*512; i += stride) cat_store_a(h, h_cat, i); break;
    case 6: for (int i = i0; i < 1024*512; i += stride) cat_store_a(sent, s_cat, i); break;
  }
}

// =================== FUSED: gemm1 + gemm2 + softmax + cHat ==================
__global__ __launch_bounds__(512) void k_fused(
    const float* __restrict__ Af, const unsigned short* __restrict__ Wae,
    const float* __restrict__ b_ae,
    const unsigned short* __restrict__ Wcg, const float* __restrict__ b_c,
    const float* __restrict__ h_e, const float* __restrict__ W_al,
    const float* __restrict__ sent_e, const float* __restrict__ sent,
    const float* __restrict__ hvec, unsigned short* __restrict__ atten_cat){
  __shared__ __align__(16) char smem[155648];
  unsigned short* As   = (unsigned short*)smem;          // ph1 [2][96*64]
  unsigned short* Bs   = (unsigned short*)(smem + 24576);// ph1 [2][512*64]
  unsigned short* attL = (unsigned short*)smem;          // ph2 [96*512]
  unsigned short* Wcs  = (unsigned short*)(smem + 98304);// ph2 [512*32]
  float* part = (float*)(smem + 131072);
  float* lg   = (float*)(smem + 131072 + 1536);
  float* alp  = (float*)(smem + 131072 + 1536 + 512);
  float* ssum = (float*)(smem + 131072 + 1536 + 1024);

  const int tid = threadIdx.x;
  const int w = tid >> 6, l = tid & 63;
  const int wm = w >> 2, wn = w & 3;
  const int b = blockIdx.x;
  const long m0 = (long)b * BM;
  const int g = l >> 4, r15 = l & 15;
  const int rs = r15 & 7;

  f32x4 acc[3][8];
#pragma unroll
  for (int i = 0; i < 3; ++i)
#pragma unroll
    for (int j = 0; j < 8; ++j) acc[i][j] = f32x4{0.f,0.f,0.f,0.f};

  // ---------------- phase 1: counted-vmcnt pipeline ------------------------
  {
    const int brow_in = l >> 3;
    const int bswz = (l & 7) ^ brow_in;
    const unsigned short* bbase = Wae + (long)(w*64 + brow_in) * FDIM + bswz*8;
    int aswz[3];
    const float* abase[3];
#pragma unroll
    for (int s = 0; s < 3; ++s) {
      int c = tid + s*512;
      int arow = c >> 4, akq = c & 15;
      abase[s] = Af + (m0 + arow)*FDIM + akq*4;
      aswz[s] = arow*BK + ((akq ^ ((arow&7)<<1))<<2);
    }
    const int NT = FDIM / BK;  // 32
    float4 d0,d1,d2, e0,e1,e2;
    float4 f0 = {0,0,0,0}, f1 = {0,0,0,0}, f2 = {0,0,0,0};

    {
      float4 c0 = *reinterpret_cast<const float4*>(abase[0]);
      float4 c1 = *reinterpret_cast<const float4*>(abase[1]);
      float4 c2 = *reinterpret_cast<const float4*>(abase[2]);
      SCHED0;
#pragma unroll
      for (int q = 0; q < 8; ++q)
        gld_lds16(bbase + (long)q*8*FDIM, Bs + (w*8+q)*512);
      SCHED0;
      d0 = *reinterpret_cast<const float4*>(abase[0] + BK);
      d1 = *reinterpret_cast<const float4*>(abase[1] + BK);
      d2 = *reinterpret_cast<const float4*>(abase[2] + BK);
      e0 = *reinterpret_cast<const float4*>(abase[0] + 2*BK);
      e1 = *reinterpret_cast<const float4*>(abase[1] + 2*BK);
      e2 = *reinterpret_cast<const float4*>(abase[2] + 2*BK);
      SCHED0;
      ushort4 p0; p0.x=f2bfn(c0.x); p0.y=f2bfn(c0.y); p0.z=f2bfn(c0.z); p0.w=f2bfn(c0.w);
      ushort4 p1; p1.x=f2bfn(c1.x); p1.y=f2bfn(c1.y); p1.z=f2bfn(c1.z); p1.w=f2bfn(c1.w);
      ushort4 p2; p2.x=f2bfn(c2.x); p2.y=f2bfn(c2.y); p2.z=f2bfn(c2.z); p2.w=f2bfn(c2.w);
      *reinterpret_cast<ushort4*>(&As[aswz[0]]) = p0;
      *reinterpret_cast<ushort4*>(&As[aswz[1]]) = p1;
      *reinterpret_cast<ushort4*>(&As[aswz[2]]) = p2;
      WAITV6; WAITL0; SCHED0; SBAR; SCHED0;
    }

    int cb = 0;
    for (int kt = 0; kt < NT; ++kt) {
      const int nb = cb ^ 1;
      if (kt + 1 < NT) {
        const long kof = (long)(kt+1) * BK;
#pragma unroll
        for (int q = 0; q < 8; ++q)
          gld_lds16(bbase + (long)q*8*FDIM + kof, Bs + nb*32768 + (w*8+q)*512);
      }
      SCHED0;
      if (kt + 3 < NT) {
        const long kof = (long)(kt+3) * BK;
        f0 = *reinterpret_cast<const float4*>(abase[0] + kof);
        f1 = *reinterpret_cast<const float4*>(abase[1] + kof);
        f2 = *reinterpret_cast<const float4*>(abase[2] + kof);
      }
      SCHED0;
#pragma unroll
      for (int hh = 0; hh < 2; ++hh) {
        const int ko = ((g + 4*hh) ^ rs) << 3;
        bf16x8 afr[3], bfr[8];
#pragma unroll
        for (int i = 0; i < 3; ++i)
          afr[i] = *reinterpret_cast<const bf16x8*>(&As[cb*6144 + (wm*48 + i*16 + r15)*BK + ko]);
#pragma unroll
        for (int j = 0; j < 8; ++j)
          bfr[j] = *reinterpret_cast<const bf16x8*>(&Bs[cb*32768 + (wn*128 + j*16 + r15)*BK + ko]);
        __builtin_amdgcn_s_setprio(1);
#pragma unroll
        for (int i = 0; i < 3; ++i)
#pragma unroll
          for (int j = 0; j < 8; ++j)
            acc[i][j] = mfma16(afr[i], bfr[j], acc[i][j]);
        __builtin_amdgcn_s_setprio(0);
      }
      if (kt + 1 < NT) {
        ushort4 p0; p0.x=f2bfn(d0.x); p0.y=f2bfn(d0.y); p0.z=f2bfn(d0.z); p0.w=f2bfn(d0.w);
        ushort4 p1; p1.x=f2bfn(d1.x); p1.y=f2bfn(d1.y); p1.z=f2bfn(d1.z); p1.w=f2bfn(d1.w);
        ushort4 p2; p2.x=f2bfn(d2.x); p2.y=f2bfn(d2.y); p2.z=f2bfn(d2.z); p2.w=f2bfn(d2.w);
        *reinterpret_cast<ushort4*>(&As[nb*6144 + aswz[0]]) = p0;
        *reinterpret_cast<ushort4*>(&As[nb*6144 + aswz[1]]) = p1;
        *reinterpret_cast<ushort4*>(&As[nb*6144 + aswz[2]]) = p2;
        d0=e0; d1=e1; d2=e2; e0=f0; e1=f1; e2=f2;
        if (kt + 3 < NT) { WAITV3; } else { WAITV0; }
        WAITL0; SCHED0; SBAR; SCHED0;
        cb = nb;
      }
    }
  }
  __syncthreads();
  // phase-1 epilogue: relu(acc+bias) -> attL (bf16, grp^(row&7) swizzle)
  {
    float bb[8];
#pragma unroll
    for (int j = 0; j < 8; ++j) bb[j] = b_ae[wn*128 + j*16 + r15];
#pragma unroll
    for (int i = 0; i < 3; ++i)
#pragma unroll
      for (int r = 0; r < 4; ++r) {
        int row = wm*48 + i*16 + g*4 + r;
        int rs8 = row & 7;
#pragma unroll
        for (int j = 0; j < 8; ++j) {
          int col = wn*128 + j*16 + r15;
          float x = acc[i][j][r] + bb[j];
          x = x > 0.f ? x : 0.f;
          attL[row*512 + (((col>>3) ^ rs8)<<3) + (col&7)] = f2bfn(x);
        }
      }
  }
  __syncthreads();

  // ------- phase 2: att @ Wc^T, W_c reg-staged (T14), lgkm-only barriers ----
#pragma unroll
  for (int i = 0; i < 3; ++i)
#pragma unroll
    for (int j = 0; j < 8; ++j) acc[i][j] = f32x4{0.f,0.f,0.f,0.f};
  {
    const int crow = l >> 2;
    const int bsl2 = (l & 3) ^ ((l >> 3) & 3);
    const int rs2 = (r15 >> 1) & 3;
    uint4 rr0, rr1, rr2, rr3;
    rr0 = *reinterpret_cast<const uint4*>(Wcg + (long)(w*64 + 0*16 + crow)*RDIM + bsl2*8);
    rr1 = *reinterpret_cast<const uint4*>(Wcg + (long)(w*64 + 1*16 + crow)*RDIM + bsl2*8);
    rr2 = *reinterpret_cast<const uint4*>(Wcg + (long)(w*64 + 2*16 + crow)*RDIM + bsl2*8);
    rr3 = *reinterpret_cast<const uint4*>(Wcg + (long)(w*64 + 3*16 + crow)*RDIM + bsl2*8);
    for (int kt = 0; kt < 16; ++kt) {
      *reinterpret_cast<uint4*>(&Wcs[w*2048 + 0*512 + l*8]) = rr0;
      *reinterpret_cast<uint4*>(&Wcs[w*2048 + 1*512 + l*8]) = rr1;
      *reinterpret_cast<uint4*>(&Wcs[w*2048 + 2*512 + l*8]) = rr2;
      *reinterpret_cast<uint4*>(&Wcs[w*2048 + 3*512 + l*8]) = rr3;
      if (kt < 15) {
        const int k0 = (kt+1)*32;
        rr0 = *reinterpret_cast<const uint4*>(Wcg + (long)(w*64 + 0*16 + crow)*RDIM + k0 + bsl2*8);
        rr1 = *reinterpret_cast<const uint4*>(Wcg + (long)(w*64 + 1*16 + crow)*RDIM + k0 + bsl2*8);
        rr2 = *reinterpret_cast<const uint4*>(Wcg + (long)(w*64 + 2*16 + crow)*RDIM + k0 + bsl2*8);
        rr3 = *reinterpret_cast<const uint4*>(Wcg + (long)(w*64 + 3*16 + crow)*RDIM + k0 + bsl2*8);
      }
      WAITL0; SCHED0; SBAR; SCHED0;
      bf16x8 afr[3], bfr[8];
#pragma unroll
      for (int i = 0; i < 3; ++i) {
        int ra = wm*48 + i*16 + r15;
        int grp = (kt<<2) + g;
        afr[i] = *reinterpret_cast<const bf16x8*>(&attL[ra*512 + ((grp ^ rs)<<3)]);
      }
#pragma unroll
      for (int j = 0; j < 8; ++j)
        bfr[j] = *reinterpret_cast<const bf16x8*>(&Wcs[(wn*128 + j*16 + r15)*32 + ((g ^ rs2)<<3)]);
      __builtin_amdgcn_s_setprio(1);
#pragma unroll
      for (int i = 0; i < 3; ++i)
#pragma unroll
        for (int j = 0; j < 8; ++j)
          acc[i][j] = mfma16(afr[i], bfr[j], acc[i][j]);
      __builtin_amdgcn_s_setprio(0);
      WAITL0; SCHED0; SBAR; SCHED0;
    }
  }
  // logits epilogue
  {
    const float* hrow = h_e + (long)b * RDIM;
    float bb2[8], wa[8], he[8];
#pragma unroll
    for (int j = 0; j < 8; ++j) {
      int n = wn*128 + j*16 + r15;
      bb2[j] = b_c[n]; wa[j] = W_al[n]; he[j] = hrow[n];
    }
#pragma unroll
    for (int i = 0; i < 3; ++i)
#pragma unroll
      for (int r = 0; r < 4; ++r) {
        int lrow = wm*48 + i*16 + g*4 + r;
        float s = 0.f;
#pragma unroll
        for (int j = 0; j < 8; ++j) {
          float x = acc[i][j][r] + bb2[j] + he[j];
          s += fast_tanh(x) * wa[j];
        }
        s += __shfl_xor(s, 1); s += __shfl_xor(s, 2);
        s += __shfl_xor(s, 4); s += __shfl_xor(s, 8);
        if (r15 == 0) part[lrow*4 + wn] = s;
      }
  }
  __syncthreads();
  if (tid < 96)
    lg[1+tid] = part[tid*4+0] + part[tid*4+1] + part[tid*4+2] + part[tid*4+3];
  if (tid < 64) {
    float s = 0.f;
    for (int a = tid; a < 512; a += 64)
      s += fast_tanh(sent_e[(long)b*512 + a] + h_e[(long)b*512 + a]) * W_al[a];
    s += __shfl_xor(s, 1); s += __shfl_xor(s, 2); s += __shfl_xor(s, 4);
    s += __shfl_xor(s, 8); s += __shfl_xor(s, 16); s += __shfl_xor(s, 32);
    if (tid == 0) lg[0] = s;
  }
  __syncthreads();
  if (tid < 64) {
    float m = -1e30f;
    for (int i = tid; i < 97; i += 64) m = fmaxf(m, lg[i]);
#pragma unroll
    for (int k = 1; k < 64; k <<= 1) m = fmaxf(m, __shfl_xor(m, k));
    float ss = 0.f;
    for (int i = tid; i < 97; i += 64) { float e = __expf(lg[i] - m); alp[i] = e; ss += e; }
#pragma unroll
    for (int k = 1; k < 64; k <<= 1) ss += __shfl_xor(ss, k);
    if (tid == 0) ssum[0] = ss;
  }
  __syncthreads();
  if (tid < 97) alp[tid] *= (1.f / ssum[0]);
  __syncthreads();
  {
    const int col = tid;
    const int cg = col >> 3, ch = col & 7;
    float accv = alp[0] * sent[(long)b*512 + col];
#pragma unroll 4
    for (int s = 0; s < SDIM; ++s)
      accv += alp[s+1] * bf2f(attL[s*512 + ((cg ^ (s&7))<<3) + ch]);
    float x = accv + hvec[(long)b*512 + col];
    unsigned short hi = f2bf(x);
    unsigned short lo = f2bf(x - bf2f(hi));
    unsigned short* pp = atten_cat + (long)b*1536 + col;
    pp[0] = hi; pp[512] = lo; pp[1024] = hi;
  }
}

// ---------------- small GEMM body (K=1536 hi/lo-cat), dbuf ------------------
__device__ __forceinline__ void small_gemm_body(
    const unsigned short* __restrict__ Abf, const unsigned short* __restrict__ Wb,
    const float* __restrict__ bias, float* __restrict__ Cout, int do_tanh, int bx,
    unsigned short* As, unsigned short* Bs){
  const int tid = threadIdx.x;
  const int w = tid >> 6, l = tid & 63;
  const int wm = w >> 1, wn = w & 1;
  const int m0 = (bx >> 3) * 64, n0 = (bx & 7) * 64;
  const int K = 1536;
  f32x4 acc[2][2];
#pragma unroll
  for (int i = 0; i < 2; ++i)
#pragma unroll
    for (int j = 0; j < 2; ++j) acc[i][j] = f32x4{0.f,0.f,0.f,0.f};

  const int crow = l >> 2;
  const int bsl = (l & 3) ^ ((l >> 3) & 3);
  const unsigned short* arow_p = Abf + (long)(m0 + w*16 + crow)*K + bsl*8;
  const unsigned short* brow_p = Wb  + (long)(n0 + w*16 + crow)*K + bsl*8;

  gld_lds16(arow_p, As + w*512);
  gld_lds16(brow_p, Bs + w*512);
  __syncthreads();
  int cb = 0;
  for (int kt = 0; kt < 48; ++kt) {
    const int nb = cb ^ 1;
    if (kt + 1 < 48) {
      const int k0 = (kt+1) * 32;
      gld_lds16(arow_p + k0, As + nb*2048 + w*512);
      gld_lds16(brow_p + k0, Bs + nb*2048 + w*512);
    }
    bf16x8 afr[2], bfr[2];
    const int g = l >> 4, r15 = l & 15;
    const int rs2 = (r15 >> 1) & 3;
#pragma unroll
    for (int i = 0; i < 2; ++i)
      afr[i] = *reinterpret_cast<const bf16x8*>(As + cb*2048 + (wm*32 + i*16 + r15)*32 + ((g ^ rs2)*8));
#pragma unroll
    for (int j = 0; j < 2; ++j)
      bfr[j] = *reinterpret_cast<const bf16x8*>(Bs + cb*2048 + (wn*32 + j*16 + r15)*32 + ((g ^ rs2)*8));
#pragma unroll
    for (int i = 0; i < 2; ++i)
#pragma unroll
      for (int j = 0; j < 2; ++j)
        acc[i][j] = mfma16(afr[i], bfr[j], acc[i][j]);
    if (kt + 1 < 48) { __syncthreads(); cb = nb; }
  }
  const int r15 = l & 15, g = l >> 4;
#pragma unroll
  for (int i = 0; i < 2; ++i)
#pragma unroll
    for (int r = 0; r < 4; ++r) {
      int m = m0 + wm*32 + i*16 + g*4 + r;
#pragma unroll
      for (int j = 0; j < 2; ++j) {
        int n = n0 + wn*32 + j*16 + r15;
        float x = acc[i][j][r] + bias[n];
        if (do_tanh) x = fast_tanh(x);
        Cout[(long)m * 512 + n] = x;
      }
    }
}

__global__ __launch_bounds__(256) void k_gemm_small(
    const unsigned short* __restrict__ Abf, const unsigned short* __restrict__ Wb,
    const float* __restrict__ bias, float* __restrict__ Cout, int do_tanh){
  __shared__ __align__(16) unsigned short As[2*64*32];
  __shared__ __align__(16) unsigned short Bs[2*64*32];
  small_gemm_body(Abf, Wb, bias, Cout, do_tanh, blockIdx.x, As, Bs);
}

__global__ __launch_bounds__(256) void k_embed2(
    const unsigned short* __restrict__ h_cat, const unsigned short* __restrict__ W_h_cat,
    const float* __restrict__ b_h, float* __restrict__ h_e,
    const unsigned short* __restrict__ s_cat, const unsigned short* __restrict__ W_s_cat,
    const float* __restrict__ b_s, float* __restrict__ sent_e){
  __shared__ __align__(16) unsigned short As[2*64*32];
  __shared__ __align__(16) unsigned short Bs[2*64*32];
  if (blockIdx.y == 0) small_gemm_body(h_cat, W_h_cat, b_h, h_e, 0, blockIdx.x, As, Bs);
  else                 small_gemm_body(s_cat, W_s_cat, b_s, sent_e, 0, blockIdx.x, As, Bs);
}

extern "C" void kernel_launch(void* const* d_in, const int* in_sizes, int n_in,
                              void* d_out, int out_size, void* d_ws, size_t ws_size,
                              hipStream_t stream){
  (void)in_sizes; (void)n_in; (void)out_size; (void)ws_size;
  const float* h    = (const float*)d_in[0];
  const float* sent = (const float*)d_in[1];
  const float* feats= (const float*)d_in[2];
  const float* W_ae = (const float*)d_in[3];
  const float* b_ae = (const float*)d_in[4];
  const float* W_c  = (const float*)d_in[5];
  const float* b_c  = (const float*)d_in[6];
  const float* W_s  = (const float*)d_in[7];
  const float* b_s  = (const float*)d_in[8];
  const float* W_h  = (const float*)d_in[9];
  const float* b_h  = (const float*)d_in[10];
  const float* W_al = (const float*)d_in[11];
  const float* W_o  = (const float*)d_in[13];
  const float* b_o  = (const float*)d_in[14];
  float* out = (float*)d_out;

  char* p = (char*)d_ws;
  unsigned short* W_ae_bf = (unsigned short*)p; p += (size_t)512*2048*2;
  unsigned short* W_c_bf  = (unsigned short*)p; p += (size_t)512*512*2;
  unsigned short* W_s_cat = (unsigned short*)p; p += (size_t)512*1536*2;
  unsigned short* W_h_cat = (unsigned short*)p; p += (size_t)512*1536*2;
  unsigned short* W_o_cat = (unsigned short*)p; p += (size_t)512*1536*2;
  unsigned short* h_cat   = (unsigned short*)p; p += (size_t)1024*1536*2;
  unsigned short* s_cat   = (unsigned short*)p; p += (size_t)1024*1536*2;
  unsigned short* at_cat  = (unsigned short*)p; p += (size_t)1024*1536*2;
  float* h_e    = (float*)p; p += (size_t)1024*512*4;
  float* sent_e = (float*)p; p += (size_t)1024*512*4;

  k_convert<<<dim3(1024,7), 256, 0, stream>>>(W_ae, W_c, W_s, W_h, W_o, h, sent,
        W_ae_bf, W_c_bf, W_s_cat, W_h_cat, W_o_cat, h_cat, s_cat);
  k_embed2<<<dim3(128,2), 256, 0, stream>>>(h_cat, W_h_cat, b_h, h_e,
                                            s_cat, W_s_cat, b_s, sent_e);
  k_fused<<<1024, 512, 0, stream>>>(feats, W_ae_bf, b_ae, W_c_bf, b_c,
                                    h_e, W_al, sent_e, sent, h, at_cat);
  k_gemm_small<<<128, 256, 0, stream>>>(at_cat, W_o_cat, b_o, out, 1);
}

// Round 12
// 412.484 us; speedup vs baseline: 1.2243x; 1.0155x over previous
//
#include <hip/hip_runtime.h>

#define M1 98304
#define RDIM 512
#define FDIM 2048
#define SDIM 96
#define BM 96
#define BK 64

typedef __attribute__((ext_vector_type(8))) __bf16 bf16x8;
typedef __attribute__((ext_vector_type(4))) float f32x4;

#define WAITV6 asm volatile("s_waitcnt vmcnt(6)" ::: "memory")
#define WAITV3 asm volatile("s_waitcnt vmcnt(3)" ::: "memory")
#define WAITV0 asm volatile("s_waitcnt vmcnt(0)" ::: "memory")
#define WAITL0 asm volatile("s_waitcnt lgkmcnt(0)" ::: "memory")
#define SBAR   __builtin_amdgcn_s_barrier()
#define SCHED0 __builtin_amdgcn_sched_barrier(0)

__device__ __forceinline__ float bf2f(unsigned short u){
  union { unsigned int i; float f; } v; v.i = ((unsigned int)u) << 16; return v.f;
}
__device__ __forceinline__ unsigned short f2bf(float f){
  union { float f; unsigned int i; } v; v.f = f;
  unsigned int r = v.i + 0x7FFFu + ((v.i >> 16) & 1u);
  return (unsigned short)(r >> 16);
}
__device__ __forceinline__ unsigned short f2bfn(float f){
  __bf16 b = (__bf16)f;
  return __builtin_bit_cast(unsigned short, b);
}
__device__ __forceinline__ float fast_tanh(float x){
  float e = __expf(2.f * x);
  return 1.f - 2.f / (e + 1.f);
}
__device__ __forceinline__ void gld_lds16(const void* g, void* l){
  __builtin_amdgcn_global_load_lds((const __attribute__((address_space(1))) void*)g,
                                   (__attribute__((address_space(3))) void*)l, 16, 0, 0);
}
__device__ __forceinline__ f32x4 mfma16(bf16x8 a, bf16x8 b, f32x4 c){
  return __builtin_amdgcn_mfma_f32_16x16x32_bf16(a, b, c, 0, 0, 0);
}

// ---------------- convert / split kernels ----------------
__device__ __forceinline__ void cat_store_a(const float* __restrict__ src,
                                            unsigned short* __restrict__ dst, int idx){
  float x = src[idx];
  int r = idx >> 9, c = idx & 511;
  unsigned short hi = f2bf(x);
  unsigned short lo = f2bf(x - bf2f(hi));
  unsigned short* p = dst + (long)r * 1536 + c;
  p[0] = hi; p[512] = lo; p[1024] = hi;
}
__device__ __forceinline__ void cat_store_w(const float* __restrict__ src,
                                            unsigned short* __restrict__ dst, int idx){
  float x = src[idx];
  int r = idx >> 9, c = idx & 511;
  unsigned short hi = f2bf(x);
  unsigned short lo = f2bf(x - bf2f(hi));
  unsigned short* p = dst + (long)r * 1536 + c;
  p[0] = hi; p[512] = hi; p[1024] = lo;
}

__global__ void k_convert(const float* W_ae, const float* W_c, const float* W_s,
                          const float* W_h, const float* W_o,
                          const float* h, const float* sent,
                          unsigned short* W_ae_bf, unsigned short* W_c_bf,
                          unsigned short* W_s_cat, unsigned short* W_h_cat,
                          unsigned short* W_o_cat, unsigned short* h_cat,
                          unsigned short* s_cat){
  const int stride = 1024 * 256;
  int i0 = blockIdx.x * 256 + threadIdx.x;
  switch (blockIdx.y) {
    case 0: for (int i = i0; i < 512*2048; i += stride) W_ae_bf[i] = f2bf(W_ae[i]); break;
    case 1: for (int i = i0; i < 512*512;  i += stride) W_c_bf[i]  = f2bf(W_c[i]);  break;
    case 2: for (int i = i0; i < 512*512;  i += stride) cat_store_w(W_s, W_s_cat, i); break;
    case 3: for (int i = i0; i < 512*512;  i += stride) cat_store_w(W_h, W_h_cat, i); break;
    case 4: for (int i = i0; i < 512*512;  i += stride) cat_store_w(W_o, W_o_cat, i); break;
    case 5: for (int i = i0; i < 1024*512; i += stride) cat_store_a(h, h_cat, i); break;
    case 6: for (int i = i0; i < 1024*512; i += stride) cat_store_a(sent, s_cat, i); break;
  }
}

// ====== FUSED (1024 threads, 16 waves = 2M x 8N): gemm1+gemm2+softmax+cHat ==
__global__ __launch_bounds__(1024, 4) void k_fused(
    const float* __restrict__ Af, const unsigned short* __restrict__ Wae,
    const float* __restrict__ b_ae,
    const unsigned short* __restrict__ Wcg, const float* __restrict__ b_c,
    const float* __restrict__ h_e, const float* __restrict__ W_al,
    const float* __restrict__ sent_e, const float* __restrict__ sent,
    const float* __restrict__ hvec, unsigned short* __restrict__ atten_cat){
  __shared__ __align__(16) char smem[155648];
  unsigned short* As   = (unsigned short*)smem;          // ph1 [2][96*64]
  unsigned short* Bs   = (unsigned short*)(smem + 24576);// ph1 [2][512*64]
  unsigned short* attL = (unsigned short*)smem;          // ph2 [96*512]
  unsigned short* Wcs  = (unsigned short*)(smem + 98304);// ph2 [512*32]
  float* part = (float*)(smem + 131072);                 // [96][8]
  float* lg   = (float*)(smem + 131072 + 3072);
  float* alp  = (float*)(smem + 131072 + 3072 + 512);
  float* ssum = (float*)(smem + 131072 + 3072 + 1024);

  const int tid = threadIdx.x;
  const int w = tid >> 6, l = tid & 63;
  const int wm = w >> 3, wn = w & 7;            // 2M x 8N
  const int b = blockIdx.x;
  const long m0 = (long)b * BM;
  const int g = l >> 4, r15 = l & 15;
  const int rs = r15 & 7;

  f32x4 acc[3][4];
#pragma unroll
  for (int i = 0; i < 3; ++i)
#pragma unroll
    for (int j = 0; j < 4; ++j) acc[i][j] = f32x4{0.f,0.f,0.f,0.f};

  // ---------------- phase 1: counted-vmcnt pipeline (R8 ledger) -------------
  {
    // B staging: wave w stages rows w*32 .. w*32+31, 4 gld_lds16 per lane
    const int bswz = (l & 7) ^ (l >> 3);
    const unsigned short* bbase = Wae + (long)(w*32 + (l >> 3)) * FDIM + bswz*8;
    // A staging: 3 float2 per thread; chunk c = tid + s*1024 -> row=c>>5, kp=c&31
    int aswz[3];
    const float* abase[3];
#pragma unroll
    for (int s = 0; s < 3; ++s) {
      int c = tid + s*1024;
      int row = c >> 5, kp = c & 31;
      abase[s] = Af + (m0 + row)*FDIM + kp*2;
      aswz[s] = row*BK + (((kp>>1) ^ ((row&7)<<1))<<2) + ((kp&1)<<1);
    }
    const int NT = FDIM / BK;  // 32
    float2 d0,d1,d2, e0,e1,e2;
    float2 f0 = {0,0}, f1 = {0,0}, f2 = {0,0};

    {
      float2 c0 = *reinterpret_cast<const float2*>(abase[0]);
      float2 c1 = *reinterpret_cast<const float2*>(abase[1]);
      float2 c2 = *reinterpret_cast<const float2*>(abase[2]);
      SCHED0;
#pragma unroll
      for (int q = 0; q < 4; ++q)
        gld_lds16(bbase + (long)q*8*FDIM, Bs + w*2048 + q*512);
      SCHED0;
      d0 = *reinterpret_cast<const float2*>(abase[0] + BK);
      d1 = *reinterpret_cast<const float2*>(abase[1] + BK);
      d2 = *reinterpret_cast<const float2*>(abase[2] + BK);
      e0 = *reinterpret_cast<const float2*>(abase[0] + 2*BK);
      e1 = *reinterpret_cast<const float2*>(abase[1] + 2*BK);
      e2 = *reinterpret_cast<const float2*>(abase[2] + 2*BK);
      SCHED0;
      *reinterpret_cast<unsigned int*>(&As[aswz[0]]) =
          (unsigned int)f2bfn(c0.x) | ((unsigned int)f2bfn(c0.y) << 16);
      *reinterpret_cast<unsigned int*>(&As[aswz[1]]) =
          (unsigned int)f2bfn(c1.x) | ((unsigned int)f2bfn(c1.y) << 16);
      *reinterpret_cast<unsigned int*>(&As[aswz[2]]) =
          (unsigned int)f2bfn(c2.x) | ((unsigned int)f2bfn(c2.y) << 16);
      WAITV6; WAITL0; SCHED0; SBAR; SCHED0;
    }

    int cb = 0;
    for (int kt = 0; kt < NT; ++kt) {
      const int nb = cb ^ 1;
      if (kt + 1 < NT) {
        const long kof = (long)(kt+1) * BK;
#pragma unroll
        for (int q = 0; q < 4; ++q)
          gld_lds16(bbase + (long)q*8*FDIM + kof, Bs + nb*32768 + w*2048 + q*512);
      }
      SCHED0;
      if (kt + 3 < NT) {
        const long kof = (long)(kt+3) * BK;
        f0 = *reinterpret_cast<const float2*>(abase[0] + kof);
        f1 = *reinterpret_cast<const float2*>(abase[1] + kof);
        f2 = *reinterpret_cast<const float2*>(abase[2] + kof);
      }
      SCHED0;
#pragma unroll
      for (int hh = 0; hh < 2; ++hh) {
        const int ko = ((g + 4*hh) ^ rs) << 3;
        bf16x8 afr[3], bfr[4];
#pragma unroll
        for (int i = 0; i < 3; ++i)
          afr[i] = *reinterpret_cast<const bf16x8*>(&As[cb*6144 + (wm*48 + i*16 + r15)*BK + ko]);
#pragma unroll
        for (int j = 0; j < 4; ++j)
          bfr[j] = *reinterpret_cast<const bf16x8*>(&Bs[cb*32768 + (wn*64 + j*16 + r15)*BK + ko]);
        __builtin_amdgcn_s_setprio(1);
#pragma unroll
        for (int i = 0; i < 3; ++i)
#pragma unroll
          for (int j = 0; j < 4; ++j)
            acc[i][j] = mfma16(afr[i], bfr[j], acc[i][j]);
        __builtin_amdgcn_s_setprio(0);
      }
      if (kt + 1 < NT) {
        *reinterpret_cast<unsigned int*>(&As[nb*6144 + aswz[0]]) =
            (unsigned int)f2bfn(d0.x) | ((unsigned int)f2bfn(d0.y) << 16);
        *reinterpret_cast<unsigned int*>(&As[nb*6144 + aswz[1]]) =
            (unsigned int)f2bfn(d1.x) | ((unsigned int)f2bfn(d1.y) << 16);
        *reinterpret_cast<unsigned int*>(&As[nb*6144 + aswz[2]]) =
            (unsigned int)f2bfn(d2.x) | ((unsigned int)f2bfn(d2.y) << 16);
        d0=e0; d1=e1; d2=e2; e0=f0; e1=f1; e2=f2;
        if (kt + 3 < NT) { WAITV3; } else { WAITV0; }
        WAITL0; SCHED0; SBAR; SCHED0;
        cb = nb;
      }
    }
  }
  __syncthreads();
  // phase-1 epilogue: relu(acc+bias) -> attL (bf16, grp^(row&7) swizzle)
  {
    float bb[4];
#pragma unroll
    for (int j = 0; j < 4; ++j) bb[j] = b_ae[wn*64 + j*16 + r15];
#pragma unroll
    for (int i = 0; i < 3; ++i)
#pragma unroll
      for (int r = 0; r < 4; ++r) {
        int row = wm*48 + i*16 + g*4 + r;
        int rs8 = row & 7;
#pragma unroll
        for (int j = 0; j < 4; ++j) {
          int col = wn*64 + j*16 + r15;
          float x = acc[i][j][r] + bb[j];
          x = x > 0.f ? x : 0.f;
          attL[row*512 + (((col>>3) ^ rs8)<<3) + (col&7)] = f2bfn(x);
        }
      }
  }
  __syncthreads();

  // ------- phase 2: att @ Wc^T, W_c reg-staged (T14), lgkm-only barriers ----
#pragma unroll
  for (int i = 0; i < 3; ++i)
#pragma unroll
    for (int j = 0; j < 4; ++j) acc[i][j] = f32x4{0.f,0.f,0.f,0.f};
  {
    const int lr = l >> 2;
    const int bsl2 = (l & 3) ^ ((l >> 3) & 3);
    const int rs2 = (r15 >> 1) & 3;
    uint4 rr0, rr1;
    rr0 = *reinterpret_cast<const uint4*>(Wcg + (long)(w*32 + 0*16 + lr)*RDIM + bsl2*8);
    rr1 = *reinterpret_cast<const uint4*>(Wcg + (long)(w*32 + 1*16 + lr)*RDIM + bsl2*8);
    for (int kt = 0; kt < 16; ++kt) {
      *reinterpret_cast<uint4*>(&Wcs[w*1024 + 0*512 + l*8]) = rr0;
      *reinterpret_cast<uint4*>(&Wcs[w*1024 + 1*512 + l*8]) = rr1;
      if (kt < 15) {
        const int k0 = (kt+1)*32;
        rr0 = *reinterpret_cast<const uint4*>(Wcg + (long)(w*32 + 0*16 + lr)*RDIM + k0 + bsl2*8);
        rr1 = *reinterpret_cast<const uint4*>(Wcg + (long)(w*32 + 1*16 + lr)*RDIM + k0 + bsl2*8);
      }
      WAITL0; SCHED0; SBAR; SCHED0;
      bf16x8 afr[3], bfr[4];
#pragma unroll
      for (int i = 0; i < 3; ++i) {
        int ra = wm*48 + i*16 + r15;
        int grp = (kt<<2) + g;
        afr[i] = *reinterpret_cast<const bf16x8*>(&attL[ra*512 + ((grp ^ rs)<<3)]);
      }
#pragma unroll
      for (int j = 0; j < 4; ++j)
        bfr[j] = *reinterpret_cast<const bf16x8*>(&Wcs[(wn*64 + j*16 + r15)*32 + ((g ^ rs2)<<3)]);
      __builtin_amdgcn_s_setprio(1);
#pragma unroll
      for (int i = 0; i < 3; ++i)
#pragma unroll
        for (int j = 0; j < 4; ++j)
          acc[i][j] = mfma16(afr[i], bfr[j], acc[i][j]);
      __builtin_amdgcn_s_setprio(0);
      WAITL0; SCHED0; SBAR; SCHED0;
    }
  }
  // logits epilogue
  {
    const float* hrow = h_e + (long)b * RDIM;
    float bb2[4], wa[4], he[4];
#pragma unroll
    for (int j = 0; j < 4; ++j) {
      int n = wn*64 + j*16 + r15;
      bb2[j] = b_c[n]; wa[j] = W_al[n]; he[j] = hrow[n];
    }
#pragma unroll
    for (int i = 0; i < 3; ++i)
#pragma unroll
      for (int r = 0; r < 4; ++r) {
        int lrow = wm*48 + i*16 + g*4 + r;
        float s = 0.f;
#pragma unroll
        for (int j = 0; j < 4; ++j) {
          float x = acc[i][j][r] + bb2[j] + he[j];
          s += fast_tanh(x) * wa[j];
        }
        s += __shfl_xor(s, 1); s += __shfl_xor(s, 2);
        s += __shfl_xor(s, 4); s += __shfl_xor(s, 8);
        if (r15 == 0) part[lrow*8 + wn] = s;
      }
  }
  __syncthreads();
  if (tid < 96) {
    float s = 0.f;
#pragma unroll
    for (int q = 0; q < 8; ++q) s += part[tid*8 + q];
    lg[1+tid] = s;
  }
  if (tid < 64) {
    float s = 0.f;
    for (int a = tid; a < 512; a += 64)
      s += fast_tanh(sent_e[(long)b*512 + a] + h_e[(long)b*512 + a]) * W_al[a];
    s += __shfl_xor(s, 1); s += __shfl_xor(s, 2); s += __shfl_xor(s, 4);
    s += __shfl_xor(s, 8); s += __shfl_xor(s, 16); s += __shfl_xor(s, 32);
    if (tid == 0) lg[0] = s;
  }
  __syncthreads();
  if (tid < 64) {
    float m = -1e30f;
    for (int i = tid; i < 97; i += 64) m = fmaxf(m, lg[i]);
#pragma unroll
    for (int k = 1; k < 64; k <<= 1) m = fmaxf(m, __shfl_xor(m, k));
    float ss = 0.f;
    for (int i = tid; i < 97; i += 64) { float e = __expf(lg[i] - m); alp[i] = e; ss += e; }
#pragma unroll
    for (int k = 1; k < 64; k <<= 1) ss += __shfl_xor(ss, k);
    if (tid == 0) ssum[0] = ss;
  }
  __syncthreads();
  if (tid < 97) alp[tid] *= (1.f / ssum[0]);
  __syncthreads();
  if (tid < 512) {
    const int col = tid;
    const int cg = col >> 3, ch = col & 7;
    float accv = alp[0] * sent[(long)b*512 + col];
#pragma unroll 4
    for (int s = 0; s < SDIM; ++s)
      accv += alp[s+1] * bf2f(attL[s*512 + ((cg ^ (s&7))<<3) + ch]);
    float x = accv + hvec[(long)b*512 + col];
    unsigned short hi = f2bf(x);
    unsigned short lo = f2bf(x - bf2f(hi));
    unsigned short* pp = atten_cat + (long)b*1536 + col;
    pp[0] = hi; pp[512] = lo; pp[1024] = hi;
  }
}

// ---------------- small GEMM body (K=1536 hi/lo-cat), dbuf ------------------
__device__ __forceinline__ void small_gemm_body(
    const unsigned short* __restrict__ Abf, const unsigned short* __restrict__ Wb,
    const float* __restrict__ bias, float* __restrict__ Cout, int do_tanh, int bx,
    unsigned short* As, unsigned short* Bs){
  const int tid = threadIdx.x;
  const int w = tid >> 6, l = tid & 63;
  const int wm = w >> 1, wn = w & 1;
  const int m0 = (bx >> 3) * 64, n0 = (bx & 7) * 64;
  const int K = 1536;
  f32x4 acc[2][2];
#pragma unroll
  for (int i = 0; i < 2; ++i)
#pragma unroll
    for (int j = 0; j < 2; ++j) acc[i][j] = f32x4{0.f,0.f,0.f,0.f};

  const int crow = l >> 2;
  const int bsl = (l & 3) ^ ((l >> 3) & 3);
  const unsigned short* arow_p = Abf + (long)(m0 + w*16 + crow)*K + bsl*8;
  const unsigned short* brow_p = Wb  + (long)(n0 + w*16 + crow)*K + bsl*8;

  gld_lds16(arow_p, As + w*512);
  gld_lds16(brow_p, Bs + w*512);
  __syncthreads();
  int cb = 0;
  for (int kt = 0; kt < 48; ++kt) {
    const int nb = cb ^ 1;
    if (kt + 1 < 48) {
      const int k0 = (kt+1) * 32;
      gld_lds16(arow_p + k0, As + nb*2048 + w*512);
      gld_lds16(brow_p + k0, Bs + nb*2048 + w*512);
    }
    bf16x8 afr[2], bfr[2];
    const int g = l >> 4, r15 = l & 15;
    const int rs2 = (r15 >> 1) & 3;
#pragma unroll
    for (int i = 0; i < 2; ++i)
      afr[i] = *reinterpret_cast<const bf16x8*>(As + cb*2048 + (wm*32 + i*16 + r15)*32 + ((g ^ rs2)*8));
#pragma unroll
    for (int j = 0; j < 2; ++j)
      bfr[j] = *reinterpret_cast<const bf16x8*>(Bs + cb*2048 + (wn*32 + j*16 + r15)*32 + ((g ^ rs2)*8));
#pragma unroll
    for (int i = 0; i < 2; ++i)
#pragma unroll
      for (int j = 0; j < 2; ++j)
        acc[i][j] = mfma16(afr[i], bfr[j], acc[i][j]);
    if (kt + 1 < 48) { __syncthreads(); cb = nb; }
  }
  const int r15 = l & 15, g = l >> 4;
#pragma unroll
  for (int i = 0; i < 2; ++i)
#pragma unroll
    for (int r = 0; r < 4; ++r) {
      int m = m0 + wm*32 + i*16 + g*4 + r;
#pragma unroll
      for (int j = 0; j < 2; ++j) {
        int n = n0 + wn*32 + j*16 + r15;
        float x = acc[i][j][r] + bias[n];
        if (do_tanh) x = fast_tanh(x);
        Cout[(long)m * 512 + n] = x;
      }
    }
}

__global__ __launch_bounds__(256) void k_gemm_small(
    const unsigned short* __restrict__ Abf, const unsigned short* __restrict__ Wb,
    const float* __restrict__ bias, float* __restrict__ Cout, int do_tanh){
  __shared__ __align__(16) unsigned short As[2*64*32];
  __shared__ __align__(16) unsigned short Bs[2*64*32];
  small_gemm_body(Abf, Wb, bias, Cout, do_tanh, blockIdx.x, As, Bs);
}

__global__ __launch_bounds__(256) void k_embed2(
    const unsigned short* __restrict__ h_cat, const unsigned short* __restrict__ W_h_cat,
    const float* __restrict__ b_h, float* __restrict__ h_e,
    const unsigned short* __restrict__ s_cat, const unsigned short* __restrict__ W_s_cat,
    const float* __restrict__ b_s, float* __restrict__ sent_e){
  __shared__ __align__(16) unsigned short As[2*64*32];
  __shared__ __align__(16) unsigned short Bs[2*64*32];
  if (blockIdx.y == 0) small_gemm_body(h_cat, W_h_cat, b_h, h_e, 0, blockIdx.x, As, Bs);
  else                 small_gemm_body(s_cat, W_s_cat, b_s, sent_e, 0, blockIdx.x, As, Bs);
}

extern "C" void kernel_launch(void* const* d_in, const int* in_sizes, int n_in,
                              void* d_out, int out_size, void* d_ws, size_t ws_size,
                              hipStream_t stream){
  (void)in_sizes; (void)n_in; (void)out_size; (void)ws_size;
  const float* h    = (const float*)d_in[0];
  const float* sent = (const float*)d_in[1];
  const float* feats= (const float*)d_in[2];
  const float* W_ae = (const float*)d_in[3];
  const float* b_ae = (const float*)d_in[4];
  const float* W_c  = (const float*)d_in[5];
  const float* b_c  = (const float*)d_in[6];
  const float* W_s  = (const float*)d_in[7];
  const float* b_s  = (const float*)d_in[8];
  const float* W_h  = (const float*)d_in[9];
  const float* b_h  = (const float*)d_in[10];
  const float* W_al = (const float*)d_in[11];
  const float* W_o  = (const float*)d_in[13];
  const float* b_o  = (const float*)d_in[14];
  float* out = (float*)d_out;

  char* p = (char*)d_ws;
  unsigned short* W_ae_bf = (unsigned short*)p; p += (size_t)512*2048*2;
  unsigned short* W_c_bf  = (unsigned short*)p; p += (size_t)512*512*2;
  unsigned short* W_s_cat = (unsigned short*)p; p += (size_t)512*1536*2;
  unsigned short* W_h_cat = (unsigned short*)p; p += (size_t)512*1536*2;
  unsigned short* W_o_cat = (unsigned short*)p; p += (size_t)512*1536*2;
  unsigned short* h_cat   = (unsigned short*)p; p += (size_t)1024*1536*2;
  unsigned short* s_cat   = (unsigned short*)p; p += (size_t)1024*1536*2;
  unsigned short* at_cat  = (unsigned short*)p; p += (size_t)1024*1536*2;
  float* h_e    = (float*)p; p += (size_t)1024*512*4;
  float* sent_e = (float*)p; p += (size_t)1024*512*4;

  k_convert<<<dim3(1024,7), 256, 0, stream>>>(W_ae, W_c, W_s, W_h, W_o, h, sent,
        W_ae_bf, W_c_bf, W_s_cat, W_h_cat, W_o_cat, h_cat, s_cat);
  k_embed2<<<dim3(128,2), 256, 0, stream>>>(h_cat, W_h_cat, b_h, h_e,
                                            s_cat, W_s_cat, b_s, sent_e);
  k_fused<<<1024, 1024, 0, stream>>>(feats, W_ae_bf, b_ae, W_c_bf, b_c,
                                     h_e, W_al, sent_e, sent, h, at_cat);
  k_gemm_small<<<128, 256, 0, stream>>>(at_cat, W_o_cat, b_o, out, 1);
}

// Round 13
// 397.507 us; speedup vs baseline: 1.2704x; 1.0377x over previous
//
#include <hip/hip_runtime.h>

#define M1 98304
#define RDIM 512
#define FDIM 2048
#define SDIM 96
#define BM 96
#define BK 64

typedef __attribute__((ext_vector_type(8))) __bf16 bf16x8;
typedef __attribute__((ext_vector_type(4))) float f32x4;
typedef __attribute__((ext_vector_type(2))) float f32x2;

#define WAITV6 asm volatile("s_waitcnt vmcnt(6)" ::: "memory")
#define WAITV3 asm volatile("s_waitcnt vmcnt(3)" ::: "memory")
#define WAITV0 asm volatile("s_waitcnt vmcnt(0)" ::: "memory")
#define WAITL0 asm volatile("s_waitcnt lgkmcnt(0)" ::: "memory")
#define SBAR   __builtin_amdgcn_s_barrier()
#define SCHED0 __builtin_amdgcn_sched_barrier(0)

__device__ __forceinline__ float bf2f(unsigned short u){
  union { unsigned int i; float f; } v; v.i = ((unsigned int)u) << 16; return v.f;
}
__device__ __forceinline__ unsigned short f2bf(float f){
  union { float f; unsigned int i; } v; v.f = f;
  unsigned int r = v.i + 0x7FFFu + ((v.i >> 16) & 1u);
  return (unsigned short)(r >> 16);
}
__device__ __forceinline__ unsigned short f2bfn(float f){
  __bf16 b = (__bf16)f;
  return __builtin_bit_cast(unsigned short, b);
}
__device__ __forceinline__ float fast_tanh(float x){
  float e = __expf(2.f * x);
  return 1.f - 2.f / (e + 1.f);
}
__device__ __forceinline__ void gld_lds16(const void* g, void* l){
  __builtin_amdgcn_global_load_lds((const __attribute__((address_space(1))) void*)g,
                                   (__attribute__((address_space(3))) void*)l, 16, 0, 0);
}
__device__ __forceinline__ f32x4 mfma16(bf16x8 a, bf16x8 b, f32x4 c){
  return __builtin_amdgcn_mfma_f32_16x16x32_bf16(a, b, c, 0, 0, 0);
}
__device__ __forceinline__ f32x2 ntload2(const float* p){
  return __builtin_nontemporal_load(reinterpret_cast<const f32x2*>(p));
}

// ---------------- convert / split kernels ----------------
__device__ __forceinline__ void cat_store_a(const float* __restrict__ src,
                                            unsigned short* __restrict__ dst, int idx){
  float x = src[idx];
  int r = idx >> 9, c = idx & 511;
  unsigned short hi = f2bf(x);
  unsigned short lo = f2bf(x - bf2f(hi));
  unsigned short* p = dst + (long)r * 1536 + c;
  p[0] = hi; p[512] = lo; p[1024] = hi;
}
__device__ __forceinline__ void cat_store_w(const float* __restrict__ src,
                                            unsigned short* __restrict__ dst, int idx){
  float x = src[idx];
  int r = idx >> 9, c = idx & 511;
  unsigned short hi = f2bf(x);
  unsigned short lo = f2bf(x - bf2f(hi));
  unsigned short* p = dst + (long)r * 1536 + c;
  p[0] = hi; p[512] = hi; p[1024] = lo;
}

__global__ void k_convert(const float* W_ae, const float* W_c, const float* W_s,
                          const float* W_h, const float* W_o,
                          const float* h, const float* sent,
                          unsigned short* W_ae_bf, unsigned short* W_c_bf,
                          unsigned short* W_s_cat, unsigned short* W_h_cat,
                          unsigned short* W_o_cat, unsigned short* h_cat,
                          unsigned short* s_cat){
  const int stride = 1024 * 256;
  int i0 = blockIdx.x * 256 + threadIdx.x;
  switch (blockIdx.y) {
    case 0: for (int i = i0; i < 512*2048; i += stride) W_ae_bf[i] = f2bf(W_ae[i]); break;
    case 1: for (int i = i0; i < 512*512;  i += stride) W_c_bf[i]  = f2bf(W_c[i]);  break;
    case 2: for (int i = i0; i < 512*512;  i += stride) cat_store_w(W_s, W_s_cat, i); break;
    case 3: for (int i = i0; i < 512*512;  i += stride) cat_store_w(W_h, W_h_cat, i); break;
    case 4: for (int i = i0; i < 512*512;  i += stride) cat_store_w(W_o, W_o_cat, i); break;
    case 5: for (int i = i0; i < 1024*512; i += stride) cat_store_a(h, h_cat, i); break;
    case 6: for (int i = i0; i < 1024*512; i += stride) cat_store_a(sent, s_cat, i); break;
  }
}

// ====== FUSED (1024 threads, 16 waves = 2M x 8N): gemm1+gemm2+softmax+cHat ==
// A-stream (feats) loaded NON-TEMPORAL to stop L2 thrash of Wae (B-panel).
__global__ __launch_bounds__(1024, 4) void k_fused(
    const float* __restrict__ Af, const unsigned short* __restrict__ Wae,
    const float* __restrict__ b_ae,
    const unsigned short* __restrict__ Wcg, const float* __restrict__ b_c,
    const float* __restrict__ h_e, const float* __restrict__ W_al,
    const float* __restrict__ sent_e, const float* __restrict__ sent,
    const float* __restrict__ hvec, unsigned short* __restrict__ atten_cat){
  __shared__ __align__(16) char smem[155648];
  unsigned short* As   = (unsigned short*)smem;          // ph1 [2][96*64]
  unsigned short* Bs   = (unsigned short*)(smem + 24576);// ph1 [2][512*64]
  unsigned short* attL = (unsigned short*)smem;          // ph2 [96*512]
  unsigned short* Wcs  = (unsigned short*)(smem + 98304);// ph2 [512*32]
  float* part = (float*)(smem + 131072);                 // [96][8]
  float* lg   = (float*)(smem + 131072 + 3072);
  float* alp  = (float*)(smem + 131072 + 3072 + 512);
  float* ssum = (float*)(smem + 131072 + 3072 + 1024);

  const int tid = threadIdx.x;
  const int w = tid >> 6, l = tid & 63;
  const int wm = w >> 3, wn = w & 7;            // 2M x 8N
  const int b = blockIdx.x;
  const long m0 = (long)b * BM;
  const int g = l >> 4, r15 = l & 15;
  const int rs = r15 & 7;

  f32x4 acc[3][4];
#pragma unroll
  for (int i = 0; i < 3; ++i)
#pragma unroll
    for (int j = 0; j < 4; ++j) acc[i][j] = f32x4{0.f,0.f,0.f,0.f};

  // ---------------- phase 1: counted-vmcnt pipeline (R8 ledger) -------------
  {
    const int bswz = (l & 7) ^ (l >> 3);
    const unsigned short* bbase = Wae + (long)(w*32 + (l >> 3)) * FDIM + bswz*8;
    int aswz[3];
    const float* abase[3];
#pragma unroll
    for (int s = 0; s < 3; ++s) {
      int c = tid + s*1024;
      int row = c >> 5, kp = c & 31;
      abase[s] = Af + (m0 + row)*FDIM + kp*2;
      aswz[s] = row*BK + (((kp>>1) ^ ((row&7)<<1))<<2) + ((kp&1)<<1);
    }
    const int NT = FDIM / BK;  // 32
    f32x2 d0,d1,d2, e0,e1,e2;
    f32x2 f0 = {0,0}, f1 = {0,0}, f2 = {0,0};

    {
      f32x2 c0 = ntload2(abase[0]);
      f32x2 c1 = ntload2(abase[1]);
      f32x2 c2 = ntload2(abase[2]);
      SCHED0;
#pragma unroll
      for (int q = 0; q < 4; ++q)
        gld_lds16(bbase + (long)q*8*FDIM, Bs + w*2048 + q*512);
      SCHED0;
      d0 = ntload2(abase[0] + BK);
      d1 = ntload2(abase[1] + BK);
      d2 = ntload2(abase[2] + BK);
      e0 = ntload2(abase[0] + 2*BK);
      e1 = ntload2(abase[1] + 2*BK);
      e2 = ntload2(abase[2] + 2*BK);
      SCHED0;
      *reinterpret_cast<unsigned int*>(&As[aswz[0]]) =
          (unsigned int)f2bfn(c0.x) | ((unsigned int)f2bfn(c0.y) << 16);
      *reinterpret_cast<unsigned int*>(&As[aswz[1]]) =
          (unsigned int)f2bfn(c1.x) | ((unsigned int)f2bfn(c1.y) << 16);
      *reinterpret_cast<unsigned int*>(&As[aswz[2]]) =
          (unsigned int)f2bfn(c2.x) | ((unsigned int)f2bfn(c2.y) << 16);
      WAITV6; WAITL0; SCHED0; SBAR; SCHED0;
    }

    int cb = 0;
    for (int kt = 0; kt < NT; ++kt) {
      const int nb = cb ^ 1;
      if (kt + 1 < NT) {
        const long kof = (long)(kt+1) * BK;
#pragma unroll
        for (int q = 0; q < 4; ++q)
          gld_lds16(bbase + (long)q*8*FDIM + kof, Bs + nb*32768 + w*2048 + q*512);
      }
      SCHED0;
      if (kt + 3 < NT) {
        const long kof = (long)(kt+3) * BK;
        f0 = ntload2(abase[0] + kof);
        f1 = ntload2(abase[1] + kof);
        f2 = ntload2(abase[2] + kof);
      }
      SCHED0;
#pragma unroll
      for (int hh = 0; hh < 2; ++hh) {
        const int ko = ((g + 4*hh) ^ rs) << 3;
        bf16x8 afr[3], bfr[4];
#pragma unroll
        for (int i = 0; i < 3; ++i)
          afr[i] = *reinterpret_cast<const bf16x8*>(&As[cb*6144 + (wm*48 + i*16 + r15)*BK + ko]);
#pragma unroll
        for (int j = 0; j < 4; ++j)
          bfr[j] = *reinterpret_cast<const bf16x8*>(&Bs[cb*32768 + (wn*64 + j*16 + r15)*BK + ko]);
        __builtin_amdgcn_s_setprio(1);
#pragma unroll
        for (int i = 0; i < 3; ++i)
#pragma unroll
          for (int j = 0; j < 4; ++j)
            acc[i][j] = mfma16(afr[i], bfr[j], acc[i][j]);
        __builtin_amdgcn_s_setprio(0);
      }
      if (kt + 1 < NT) {
        *reinterpret_cast<unsigned int*>(&As[nb*6144 + aswz[0]]) =
            (unsigned int)f2bfn(d0.x) | ((unsigned int)f2bfn(d0.y) << 16);
        *reinterpret_cast<unsigned int*>(&As[nb*6144 + aswz[1]]) =
            (unsigned int)f2bfn(d1.x) | ((unsigned int)f2bfn(d1.y) << 16);
        *reinterpret_cast<unsigned int*>(&As[nb*6144 + aswz[2]]) =
            (unsigned int)f2bfn(d2.x) | ((unsigned int)f2bfn(d2.y) << 16);
        d0=e0; d1=e1; d2=e2; e0=f0; e1=f1; e2=f2;
        if (kt + 3 < NT) { WAITV3; } else { WAITV0; }
        WAITL0; SCHED0; SBAR; SCHED0;
        cb = nb;
      }
    }
  }
  __syncthreads();
  // phase-1 epilogue: relu(acc+bias) -> attL (bf16, grp^(row&7) swizzle)
  {
    float bb[4];
#pragma unroll
    for (int j = 0; j < 4; ++j) bb[j] = b_ae[wn*64 + j*16 + r15];
#pragma unroll
    for (int i = 0; i < 3; ++i)
#pragma unroll
      for (int r = 0; r < 4; ++r) {
        int row = wm*48 + i*16 + g*4 + r;
        int rs8 = row & 7;
#pragma unroll
        for (int j = 0; j < 4; ++j) {
          int col = wn*64 + j*16 + r15;
          float x = acc[i][j][r] + bb[j];
          x = x > 0.f ? x : 0.f;
          attL[row*512 + (((col>>3) ^ rs8)<<3) + (col&7)] = f2bfn(x);
        }
      }
  }
  __syncthreads();

  // ------- phase 2: att @ Wc^T, W_c reg-staged (T14), lgkm-only barriers ----
#pragma unroll
  for (int i = 0; i < 3; ++i)
#pragma unroll
    for (int j = 0; j < 4; ++j) acc[i][j] = f32x4{0.f,0.f,0.f,0.f};
  {
    const int lr = l >> 2;
    const int bsl2 = (l & 3) ^ ((l >> 3) & 3);
    const int rs2 = (r15 >> 1) & 3;
    uint4 rr0, rr1;
    rr0 = *reinterpret_cast<const uint4*>(Wcg + (long)(w*32 + 0*16 + lr)*RDIM + bsl2*8);
    rr1 = *reinterpret_cast<const uint4*>(Wcg + (long)(w*32 + 1*16 + lr)*RDIM + bsl2*8);
    for (int kt = 0; kt < 16; ++kt) {
      *reinterpret_cast<uint4*>(&Wcs[w*1024 + 0*512 + l*8]) = rr0;
      *reinterpret_cast<uint4*>(&Wcs[w*1024 + 1*512 + l*8]) = rr1;
      if (kt < 15) {
        const int k0 = (kt+1)*32;
        rr0 = *reinterpret_cast<const uint4*>(Wcg + (long)(w*32 + 0*16 + lr)*RDIM + k0 + bsl2*8);
        rr1 = *reinterpret_cast<const uint4*>(Wcg + (long)(w*32 + 1*16 + lr)*RDIM + k0 + bsl2*8);
      }
      WAITL0; SCHED0; SBAR; SCHED0;
      bf16x8 afr[3], bfr[4];
#pragma unroll
      for (int i = 0; i < 3; ++i) {
        int ra = wm*48 + i*16 + r15;
        int grp = (kt<<2) + g;
        afr[i] = *reinterpret_cast<const bf16x8*>(&attL[ra*512 + ((grp ^ rs)<<3)]);
      }
#pragma unroll
      for (int j = 0; j < 4; ++j)
        bfr[j] = *reinterpret_cast<const bf16x8*>(&Wcs[(wn*64 + j*16 + r15)*32 + ((g ^ rs2)<<3)]);
      __builtin_amdgcn_s_setprio(1);
#pragma unroll
      for (int i = 0; i < 3; ++i)
#pragma unroll
        for (int j = 0; j < 4; ++j)
          acc[i][j] = mfma16(afr[i], bfr[j], acc[i][j]);
      __builtin_amdgcn_s_setprio(0);
      WAITL0; SCHED0; SBAR; SCHED0;
    }
  }
  // logits epilogue
  {
    const float* hrow = h_e + (long)b * RDIM;
    float bb2[4], wa[4], he[4];
#pragma unroll
    for (int j = 0; j < 4; ++j) {
      int n = wn*64 + j*16 + r15;
      bb2[j] = b_c[n]; wa[j] = W_al[n]; he[j] = hrow[n];
    }
#pragma unroll
    for (int i = 0; i < 3; ++i)
#pragma unroll
      for (int r = 0; r < 4; ++r) {
        int lrow = wm*48 + i*16 + g*4 + r;
        float s = 0.f;
#pragma unroll
        for (int j = 0; j < 4; ++j) {
          float x = acc[i][j][r] + bb2[j] + he[j];
          s += fast_tanh(x) * wa[j];
        }
        s += __shfl_xor(s, 1); s += __shfl_xor(s, 2);
        s += __shfl_xor(s, 4); s += __shfl_xor(s, 8);
        if (r15 == 0) part[lrow*8 + wn] = s;
      }
  }
  __syncthreads();
  if (tid < 96) {
    float s = 0.f;
#pragma unroll
    for (int q = 0; q < 8; ++q) s += part[tid*8 + q];
    lg[1+tid] = s;
  }
  if (tid < 64) {
    float s = 0.f;
    for (int a = tid; a < 512; a += 64)
      s += fast_tanh(sent_e[(long)b*512 + a] + h_e[(long)b*512 + a]) * W_al[a];
    s += __shfl_xor(s, 1); s += __shfl_xor(s, 2); s += __shfl_xor(s, 4);
    s += __shfl_xor(s, 8); s += __shfl_xor(s, 16); s += __shfl_xor(s, 32);
    if (tid == 0) lg[0] = s;
  }
  __syncthreads();
  if (tid < 64) {
    float m = -1e30f;
    for (int i = tid; i < 97; i += 64) m = fmaxf(m, lg[i]);
#pragma unroll
    for (int k = 1; k < 64; k <<= 1) m = fmaxf(m, __shfl_xor(m, k));
    float ss = 0.f;
    for (int i = tid; i < 97; i += 64) { float e = __expf(lg[i] - m); alp[i] = e; ss += e; }
#pragma unroll
    for (int k = 1; k < 64; k <<= 1) ss += __shfl_xor(ss, k);
    if (tid == 0) ssum[0] = ss;
  }
  __syncthreads();
  if (tid < 97) alp[tid] *= (1.f / ssum[0]);
  __syncthreads();
  if (tid < 512) {
    const int col = tid;
    const int cg = col >> 3, ch = col & 7;
    float accv = alp[0] * sent[(long)b*512 + col];
#pragma unroll 4
    for (int s = 0; s < SDIM; ++s)
      accv += alp[s+1] * bf2f(attL[s*512 + ((cg ^ (s&7))<<3) + ch]);
    float x = accv + hvec[(long)b*512 + col];
    unsigned short hi = f2bf(x);
    unsigned short lo = f2bf(x - bf2f(hi));
    unsigned short* pp = atten_cat + (long)b*1536 + col;
    pp[0] = hi; pp[512] = lo; pp[1024] = hi;
  }
}

// ---------------- small GEMM body (K=1536 hi/lo-cat), dbuf ------------------
__device__ __forceinline__ void small_gemm_body(
    const unsigned short* __restrict__ Abf, const unsigned short* __restrict__ Wb,
    const float* __restrict__ bias, float* __restrict__ Cout, int do_tanh, int bx,
    unsigned short* As, unsigned short* Bs){
  const int tid = threadIdx.x;
  const int w = tid >> 6, l = tid & 63;
  const int wm = w >> 1, wn = w & 1;
  const int m0 = (bx >> 3) * 64, n0 = (bx & 7) * 64;
  const int K = 1536;
  f32x4 acc[2][2];
#pragma unroll
  for (int i = 0; i < 2; ++i)
#pragma unroll
    for (int j = 0; j < 2; ++j) acc[i][j] = f32x4{0.f,0.f,0.f,0.f};

  const int crow = l >> 2;
  const int bsl = (l & 3) ^ ((l >> 3) & 3);
  const unsigned short* arow_p = Abf + (long)(m0 + w*16 + crow)*K + bsl*8;
  const unsigned short* brow_p = Wb  + (long)(n0 + w*16 + crow)*K + bsl*8;

  gld_lds16(arow_p, As + w*512);
  gld_lds16(brow_p, Bs + w*512);
  __syncthreads();
  int cb = 0;
  for (int kt = 0; kt < 48; ++kt) {
    const int nb = cb ^ 1;
    if (kt + 1 < 48) {
      const int k0 = (kt+1) * 32;
      gld_lds16(arow_p + k0, As + nb*2048 + w*512);
      gld_lds16(brow_p + k0, Bs + nb*2048 + w*512);
    }
    bf16x8 afr[2], bfr[2];
    const int g = l >> 4, r15 = l & 15;
    const int rs2 = (r15 >> 1) & 3;
#pragma unroll
    for (int i = 0; i < 2; ++i)
      afr[i] = *reinterpret_cast<const bf16x8*>(As + cb*2048 + (wm*32 + i*16 + r15)*32 + ((g ^ rs2)*8));
#pragma unroll
    for (int j = 0; j < 2; ++j)
      bfr[j] = *reinterpret_cast<const bf16x8*>(Bs + cb*2048 + (wn*32 + j*16 + r15)*32 + ((g ^ rs2)*8));
#pragma unroll
    for (int i = 0; i < 2; ++i)
#pragma unroll
      for (int j = 0; j < 2; ++j)
        acc[i][j] = mfma16(afr[i], bfr[j], acc[i][j]);
    if (kt + 1 < 48) { __syncthreads(); cb = nb; }
  }
  const int r15 = l & 15, g = l >> 4;
#pragma unroll
  for (int i = 0; i < 2; ++i)
#pragma unroll
    for (int r = 0; r < 4; ++r) {
      int m = m0 + wm*32 + i*16 + g*4 + r;
#pragma unroll
      for (int j = 0; j < 2; ++j) {
        int n = n0 + wn*32 + j*16 + r15;
        float x = acc[i][j][r] + bias[n];
        if (do_tanh) x = fast_tanh(x);
        Cout[(long)m * 512 + n] = x;
      }
    }
}

__global__ __launch_bounds__(256) void k_gemm_small(
    const unsigned short* __restrict__ Abf, const unsigned short* __restrict__ Wb,
    const float* __restrict__ bias, float* __restrict__ Cout, int do_tanh){
  __shared__ __align__(16) unsigned short As[2*64*32];
  __shared__ __align__(16) unsigned short Bs[2*64*32];
  small_gemm_body(Abf, Wb, bias, Cout, do_tanh, blockIdx.x, As, Bs);
}

__global__ __launch_bounds__(256) void k_embed2(
    const unsigned short* __restrict__ h_cat, const unsigned short* __restrict__ W_h_cat,
    const float* __restrict__ b_h, float* __restrict__ h_e,
    const unsigned short* __restrict__ s_cat, const unsigned short* __restrict__ W_s_cat,
    const float* __restrict__ b_s, float* __restrict__ sent_e){
  __shared__ __align__(16) unsigned short As[2*64*32];
  __shared__ __align__(16) unsigned short Bs[2*64*32];
  if (blockIdx.y == 0) small_gemm_body(h_cat, W_h_cat, b_h, h_e, 0, blockIdx.x, As, Bs);
  else                 small_gemm_body(s_cat, W_s_cat, b_s, sent_e, 0, blockIdx.x, As, Bs);
}

extern "C" void kernel_launch(void* const* d_in, const int* in_sizes, int n_in,
                              void* d_out, int out_size, void* d_ws, size_t ws_size,
                              hipStream_t stream){
  (void)in_sizes; (void)n_in; (void)out_size; (void)ws_size;
  const float* h    = (const float*)d_in[0];
  const float* sent = (const float*)d_in[1];
  const float* feats= (const float*)d_in[2];
  const float* W_ae = (const float*)d_in[3];
  const float* b_ae = (const float*)d_in[4];
  const float* W_c  = (const float*)d_in[5];
  const float* b_c  = (const float*)d_in[6];
  const float* W_s  = (const float*)d_in[7];
  const float* b_s  = (const float*)d_in[8];
  const float* W_h  = (const float*)d_in[9];
  const float* b_h  = (const float*)d_in[10];
  const float* W_al = (const float*)d_in[11];
  const float* W_o  = (const float*)d_in[13];
  const float* b_o  = (const float*)d_in[14];
  float* out = (float*)d_out;

  char* p = (char*)d_ws;
  unsigned short* W_ae_bf = (unsigned short*)p; p += (size_t)512*2048*2;
  unsigned short* W_c_bf  = (unsigned short*)p; p += (size_t)512*512*2;
  unsigned short* W_s_cat = (unsigned short*)p; p += (size_t)512*1536*2;
  unsigned short* W_h_cat = (unsigned short*)p; p += (size_t)512*1536*2;
  unsigned short* W_o_cat = (unsigned short*)p; p += (size_t)512*1536*2;
  unsigned short* h_cat   = (unsigned short*)p; p += (size_t)1024*1536*2;
  unsigned short* s_cat   = (unsigned short*)p; p += (size_t)1024*1536*2;
  unsigned short* at_cat  = (unsigned short*)p; p += (size_t)1024*1536*2;
  float* h_e    = (float*)p; p += (size_t)1024*512*4;
  float* sent_e = (float*)p; p += (size_t)1024*512*4;

  k_convert<<<dim3(1024,7), 256, 0, stream>>>(W_ae, W_c, W_s, W_h, W_o, h, sent,
        W_ae_bf, W_c_bf, W_s_cat, W_h_cat, W_o_cat, h_cat, s_cat);
  k_embed2<<<dim3(128,2), 256, 0, stream>>>(h_cat, W_h_cat, b_h, h_e,
                                            s_cat, W_s_cat, b_s, sent_e);
  k_fused<<<1024, 1024, 0, stream>>>(feats, W_ae_bf, b_ae, W_c_bf, b_c,
                                     h_e, W_al, sent_e, sent, h, at_cat);
  k_gemm_small<<<128, 256, 0, stream>>>(at_cat, W_o_cat, b_o, out, 1);
}

// Round 14
// 390.545 us; speedup vs baseline: 1.2930x; 1.0178x over previous
//
#include <hip/hip_runtime.h>

#define M1 98304
#define RDIM 512
#define FDIM 2048
#define SDIM 96
#define BM 96
#define BK 64

typedef __attribute__((ext_vector_type(8))) __bf16 bf16x8;
typedef __attribute__((ext_vector_type(4))) float f32x4;
typedef __attribute__((ext_vector_type(2))) float f32x2;

#define WAITV6 asm volatile("s_waitcnt vmcnt(6)" ::: "memory")
#define WAITV3 asm volatile("s_waitcnt vmcnt(3)" ::: "memory")
#define WAITV0 asm volatile("s_waitcnt vmcnt(0)" ::: "memory")
#define WAITL0 asm volatile("s_waitcnt lgkmcnt(0)" ::: "memory")
#define SBAR   __builtin_amdgcn_s_barrier()
#define SCHED0 __builtin_amdgcn_sched_barrier(0)

__device__ __forceinline__ float bf2f(unsigned short u){
  union { unsigned int i; float f; } v; v.i = ((unsigned int)u) << 16; return v.f;
}
__device__ __forceinline__ unsigned short f2bf(float f){
  union { float f; unsigned int i; } v; v.f = f;
  unsigned int r = v.i + 0x7FFFu + ((v.i >> 16) & 1u);
  return (unsigned short)(r >> 16);
}
__device__ __forceinline__ unsigned short f2bfn(float f){
  __bf16 b = (__bf16)f;
  return __builtin_bit_cast(unsigned short, b);
}
__device__ __forceinline__ float fast_tanh(float x){
  float e = __expf(2.f * x);
  return 1.f - 2.f / (e + 1.f);
}
__device__ __forceinline__ void gld_lds16(const void* g, void* l){
  __builtin_amdgcn_global_load_lds((const __attribute__((address_space(1))) void*)g,
                                   (__attribute__((address_space(3))) void*)l, 16, 0, 0);
}
__device__ __forceinline__ f32x4 mfma16(bf16x8 a, bf16x8 b, f32x4 c){
  return __builtin_amdgcn_mfma_f32_16x16x32_bf16(a, b, c, 0, 0, 0);
}
__device__ __forceinline__ f32x2 ntload2(const float* p){
  return __builtin_nontemporal_load(reinterpret_cast<const f32x2*>(p));
}

// ---------------- convert / split kernels ----------------
__device__ __forceinline__ void cat_store_a(const float* __restrict__ src,
                                            unsigned short* __restrict__ dst, int idx){
  float x = src[idx];
  int r = idx >> 9, c = idx & 511;
  unsigned short hi = f2bf(x);
  unsigned short lo = f2bf(x - bf2f(hi));
  unsigned short* p = dst + (long)r * 1536 + c;
  p[0] = hi; p[512] = lo; p[1024] = hi;
}
__device__ __forceinline__ void cat_store_w(const float* __restrict__ src,
                                            unsigned short* __restrict__ dst, int idx){
  float x = src[idx];
  int r = idx >> 9, c = idx & 511;
  unsigned short hi = f2bf(x);
  unsigned short lo = f2bf(x - bf2f(hi));
  unsigned short* p = dst + (long)r * 1536 + c;
  p[0] = hi; p[512] = hi; p[1024] = lo;
}

__global__ void k_convert(const float* W_ae, const float* W_c, const float* W_s,
                          const float* W_h, const float* W_o,
                          const float* h, const float* sent,
                          unsigned short* W_ae_bf, unsigned short* W_c_bf,
                          unsigned short* W_s_cat, unsigned short* W_h_cat,
                          unsigned short* W_o_cat, unsigned short* h_cat,
                          unsigned short* s_cat){
  const int stride = 1024 * 256;
  int i0 = blockIdx.x * 256 + threadIdx.x;
  switch (blockIdx.y) {
    case 0: for (int i = i0; i < 512*2048; i += stride) W_ae_bf[i] = f2bf(W_ae[i]); break;
    case 1: for (int i = i0; i < 512*512;  i += stride) W_c_bf[i]  = f2bf(W_c[i]);  break;
    case 2: for (int i = i0; i < 512*512;  i += stride) cat_store_w(W_s, W_s_cat, i); break;
    case 3: for (int i = i0; i < 512*512;  i += stride) cat_store_w(W_h, W_h_cat, i); break;
    case 4: for (int i = i0; i < 512*512;  i += stride) cat_store_w(W_o, W_o_cat, i); break;
    case 5: for (int i = i0; i < 1024*512; i += stride) cat_store_a(h, h_cat, i); break;
    case 6: for (int i = i0; i < 1024*512; i += stride) cat_store_a(sent, s_cat, i); break;
  }
}

// ====== FUSED (1024 threads, 16 waves = 2M x 8N): gemm1+gemm2+softmax+cHat ==
__global__ __launch_bounds__(1024, 4) void k_fused(
    const float* __restrict__ Af, const unsigned short* __restrict__ Wae,
    const float* __restrict__ b_ae,
    const unsigned short* __restrict__ Wcg, const float* __restrict__ b_c,
    const float* __restrict__ h_e, const float* __restrict__ W_al,
    const float* __restrict__ sent_e, const float* __restrict__ sent,
    const float* __restrict__ hvec, unsigned short* __restrict__ atten_cat){
  __shared__ __align__(16) char smem[163840];            // 160 KB exactly
  unsigned short* As   = (unsigned short*)smem;          // ph1 [2][96*64]
  unsigned short* Bs   = (unsigned short*)(smem + 24576);// ph1 [2][512*64]
  unsigned short* attL = (unsigned short*)smem;          // ph2 [96*512]
  unsigned short* Wcs  = (unsigned short*)(smem + 98304);// ph2 [2][512*32] dbuf
  float* part = (float*)(smem + 98304);                  // overlay after ph2
  float* lg   = (float*)(smem + 98304 + 3072);
  float* alp  = (float*)(smem + 98304 + 3584);
  float* ssum = (float*)(smem + 98304 + 4096);

  const int tid = threadIdx.x;
  const int w = tid >> 6, l = tid & 63;
  const int wm = w >> 3, wn = w & 7;            // 2M x 8N
  const int b = blockIdx.x;
  const long m0 = (long)b * BM;
  const int g = l >> 4, r15 = l & 15;
  const int rs = r15 & 7;

  f32x4 acc[3][4];
#pragma unroll
  for (int i = 0; i < 3; ++i)
#pragma unroll
    for (int j = 0; j < 4; ++j) acc[i][j] = f32x4{0.f,0.f,0.f,0.f};

  // ---------------- phase 1: counted-vmcnt pipeline (R8 ledger, NT A) -------
  {
    const int bswz = (l & 7) ^ (l >> 3);
    const unsigned short* bbase = Wae + (long)(w*32 + (l >> 3)) * FDIM + bswz*8;
    int aswz[3];
    const float* abase[3];
#pragma unroll
    for (int s = 0; s < 3; ++s) {
      int c = tid + s*1024;
      int row = c >> 5, kp = c & 31;
      abase[s] = Af + (m0 + row)*FDIM + kp*2;
      aswz[s] = row*BK + (((kp>>1) ^ ((row&7)<<1))<<2) + ((kp&1)<<1);
    }
    const int NT = FDIM / BK;  // 32
    f32x2 d0,d1,d2, e0,e1,e2;
    f32x2 f0 = {0,0}, f1 = {0,0}, f2 = {0,0};

    {
      f32x2 c0 = ntload2(abase[0]);
      f32x2 c1 = ntload2(abase[1]);
      f32x2 c2 = ntload2(abase[2]);
      SCHED0;
#pragma unroll
      for (int q = 0; q < 4; ++q)
        gld_lds16(bbase + (long)q*8*FDIM, Bs + w*2048 + q*512);
      SCHED0;
      d0 = ntload2(abase[0] + BK);
      d1 = ntload2(abase[1] + BK);
      d2 = ntload2(abase[2] + BK);
      e0 = ntload2(abase[0] + 2*BK);
      e1 = ntload2(abase[1] + 2*BK);
      e2 = ntload2(abase[2] + 2*BK);
      SCHED0;
      *reinterpret_cast<unsigned int*>(&As[aswz[0]]) =
          (unsigned int)f2bfn(c0.x) | ((unsigned int)f2bfn(c0.y) << 16);
      *reinterpret_cast<unsigned int*>(&As[aswz[1]]) =
          (unsigned int)f2bfn(c1.x) | ((unsigned int)f2bfn(c1.y) << 16);
      *reinterpret_cast<unsigned int*>(&As[aswz[2]]) =
          (unsigned int)f2bfn(c2.x) | ((unsigned int)f2bfn(c2.y) << 16);
      WAITV6; WAITL0; SCHED0; SBAR; SCHED0;
    }

    int cb = 0;
    for (int kt = 0; kt < NT; ++kt) {
      const int nb = cb ^ 1;
      if (kt + 1 < NT) {
        const long kof = (long)(kt+1) * BK;
#pragma unroll
        for (int q = 0; q < 4; ++q)
          gld_lds16(bbase + (long)q*8*FDIM + kof, Bs + nb*32768 + w*2048 + q*512);
      }
      SCHED0;
      if (kt + 3 < NT) {
        const long kof = (long)(kt+3) * BK;
        f0 = ntload2(abase[0] + kof);
        f1 = ntload2(abase[1] + kof);
        f2 = ntload2(abase[2] + kof);
      }
      SCHED0;
#pragma unroll
      for (int hh = 0; hh < 2; ++hh) {
        const int ko = ((g + 4*hh) ^ rs) << 3;
        bf16x8 afr[3], bfr[4];
#pragma unroll
        for (int i = 0; i < 3; ++i)
          afr[i] = *reinterpret_cast<const bf16x8*>(&As[cb*6144 + (wm*48 + i*16 + r15)*BK + ko]);
#pragma unroll
        for (int j = 0; j < 4; ++j)
          bfr[j] = *reinterpret_cast<const bf16x8*>(&Bs[cb*32768 + (wn*64 + j*16 + r15)*BK + ko]);
        __builtin_amdgcn_s_setprio(1);
#pragma unroll
        for (int i = 0; i < 3; ++i)
#pragma unroll
          for (int j = 0; j < 4; ++j)
            acc[i][j] = mfma16(afr[i], bfr[j], acc[i][j]);
        __builtin_amdgcn_s_setprio(0);
      }
      if (kt + 1 < NT) {
        *reinterpret_cast<unsigned int*>(&As[nb*6144 + aswz[0]]) =
            (unsigned int)f2bfn(d0.x) | ((unsigned int)f2bfn(d0.y) << 16);
        *reinterpret_cast<unsigned int*>(&As[nb*6144 + aswz[1]]) =
            (unsigned int)f2bfn(d1.x) | ((unsigned int)f2bfn(d1.y) << 16);
        *reinterpret_cast<unsigned int*>(&As[nb*6144 + aswz[2]]) =
            (unsigned int)f2bfn(d2.x) | ((unsigned int)f2bfn(d2.y) << 16);
        d0=e0; d1=e1; d2=e2; e0=f0; e1=f1; e2=f2;
        if (kt + 3 < NT) { WAITV3; } else { WAITV0; }
        WAITL0; SCHED0; SBAR; SCHED0;
        cb = nb;
      }
    }
  }
  __syncthreads();
  // phase-1 epilogue: relu(acc+bias) -> attL (bf16, grp^(row&7) swizzle)
  {
    float bb[4];
#pragma unroll
    for (int j = 0; j < 4; ++j) bb[j] = b_ae[wn*64 + j*16 + r15];
#pragma unroll
    for (int i = 0; i < 3; ++i)
#pragma unroll
      for (int r = 0; r < 4; ++r) {
        int row = wm*48 + i*16 + g*4 + r;
        int rs8 = row & 7;
#pragma unroll
        for (int j = 0; j < 4; ++j) {
          int col = wn*64 + j*16 + r15;
          float x = acc[i][j][r] + bb[j];
          x = x > 0.f ? x : 0.f;
          attL[row*512 + (((col>>3) ^ rs8)<<3) + (col&7)] = f2bfn(x);
        }
      }
  }
  __syncthreads();

  // ------- phase 2: att @ Wc^T, Wcs double-buffered gld_lds (R6 staging) ----
#pragma unroll
  for (int i = 0; i < 3; ++i)
#pragma unroll
    for (int j = 0; j < 4; ++j) acc[i][j] = f32x4{0.f,0.f,0.f,0.f};
  {
    const int lr = l >> 2;
    const int bsl2 = (l & 3) ^ ((l >> 3) & 3);
    const int rs2 = (r15 >> 1) & 3;
    // prologue: stage kt=0 -> buf 0 (2 gld_lds per wave)
#pragma unroll
    for (int q = 0; q < 2; ++q)
      gld_lds16(Wcg + (long)(w*32 + q*16 + lr)*RDIM + bsl2*8,
                Wcs + w*1024 + q*512);
    __syncthreads();
    int cb = 0;
    for (int kt = 0; kt < 16; ++kt) {
      const int nb = cb ^ 1;
      if (kt + 1 < 16) {
        const int k0 = (kt+1)*32;
#pragma unroll
        for (int q = 0; q < 2; ++q)
          gld_lds16(Wcg + (long)(w*32 + q*16 + lr)*RDIM + k0 + bsl2*8,
                    Wcs + nb*16384 + w*1024 + q*512);
      }
      bf16x8 afr[3], bfr[4];
#pragma unroll
      for (int i = 0; i < 3; ++i) {
        int ra = wm*48 + i*16 + r15;
        int grp = (kt<<2) + g;
        afr[i] = *reinterpret_cast<const bf16x8*>(&attL[ra*512 + ((grp ^ rs)<<3)]);
      }
#pragma unroll
      for (int j = 0; j < 4; ++j)
        bfr[j] = *reinterpret_cast<const bf16x8*>(&Wcs[cb*16384 + (wn*64 + j*16 + r15)*32 + ((g ^ rs2)<<3)]);
      __builtin_amdgcn_s_setprio(1);
#pragma unroll
      for (int i = 0; i < 3; ++i)
#pragma unroll
        for (int j = 0; j < 4; ++j)
          acc[i][j] = mfma16(afr[i], bfr[j], acc[i][j]);
      __builtin_amdgcn_s_setprio(0);
      __syncthreads();      // also guards part/lg overlay after last iter
      cb = nb;
    }
  }
  // logits epilogue (part/lg overlay the dead Wcs region)
  {
    const float* hrow = h_e + (long)b * RDIM;
    float bb2[4], wa[4], he[4];
#pragma unroll
    for (int j = 0; j < 4; ++j) {
      int n = wn*64 + j*16 + r15;
      bb2[j] = b_c[n]; wa[j] = W_al[n]; he[j] = hrow[n];
    }
#pragma unroll
    for (int i = 0; i < 3; ++i)
#pragma unroll
      for (int r = 0; r < 4; ++r) {
        int lrow = wm*48 + i*16 + g*4 + r;
        float s = 0.f;
#pragma unroll
        for (int j = 0; j < 4; ++j) {
          float x = acc[i][j][r] + bb2[j] + he[j];
          s += fast_tanh(x) * wa[j];
        }
        s += __shfl_xor(s, 1); s += __shfl_xor(s, 2);
        s += __shfl_xor(s, 4); s += __shfl_xor(s, 8);
        if (r15 == 0) part[lrow*8 + wn] = s;
      }
  }
  __syncthreads();
  if (tid < 96) {
    float s = 0.f;
#pragma unroll
    for (int q = 0; q < 8; ++q) s += part[tid*8 + q];
    lg[1+tid] = s;
  }
  if (tid < 64) {
    float s = 0.f;
    for (int a = tid; a < 512; a += 64)
      s += fast_tanh(sent_e[(long)b*512 + a] + h_e[(long)b*512 + a]) * W_al[a];
    s += __shfl_xor(s, 1); s += __shfl_xor(s, 2); s += __shfl_xor(s, 4);
    s += __shfl_xor(s, 8); s += __shfl_xor(s, 16); s += __shfl_xor(s, 32);
    if (tid == 0) lg[0] = s;
  }
  __syncthreads();
  if (tid < 64) {
    float m = -1e30f;
    for (int i = tid; i < 97; i += 64) m = fmaxf(m, lg[i]);
#pragma unroll
    for (int k = 1; k < 64; k <<= 1) m = fmaxf(m, __shfl_xor(m, k));
    float ss = 0.f;
    for (int i = tid; i < 97; i += 64) { float e = __expf(lg[i] - m); alp[i] = e; ss += e; }
#pragma unroll
    for (int k = 1; k < 64; k <<= 1) ss += __shfl_xor(ss, k);
    if (tid == 0) ssum[0] = ss;
  }
  __syncthreads();
  if (tid < 97) alp[tid] *= (1.f / ssum[0]);
  __syncthreads();
  if (tid < 512) {
    const int col = tid;
    const int cg = col >> 3, ch = col & 7;
    float accv = alp[0] * sent[(long)b*512 + col];
#pragma unroll 4
    for (int s = 0; s < SDIM; ++s)
      accv += alp[s+1] * bf2f(attL[s*512 + ((cg ^ (s&7))<<3) + ch]);
    float x = accv + hvec[(long)b*512 + col];
    unsigned short hi = f2bf(x);
    unsigned short lo = f2bf(x - bf2f(hi));
    unsigned short* pp = atten_cat + (long)b*1536 + col;
    pp[0] = hi; pp[512] = lo; pp[1024] = hi;
  }
}

// ------------- small GEMM body (K=1536 hi/lo-cat), BK=64 dbuf ---------------
__device__ __forceinline__ void small_gemm_body(
    const unsigned short* __restrict__ Abf, const unsigned short* __restrict__ Wb,
    const float* __restrict__ bias, float* __restrict__ Cout, int do_tanh, int bx,
    unsigned short* As, unsigned short* Bs){
  const int tid = threadIdx.x;
  const int w = tid >> 6, l = tid & 63;
  const int wm = w >> 1, wn = w & 1;
  const int m0 = (bx >> 3) * 64, n0 = (bx & 7) * 64;
  const int K = 1536;
  const int g = l >> 4, r15 = l & 15;
  const int rs = r15 & 7;
  f32x4 acc[2][2];
#pragma unroll
  for (int i = 0; i < 2; ++i)
#pragma unroll
    for (int j = 0; j < 2; ++j) acc[i][j] = f32x4{0.f,0.f,0.f,0.f};

  const int brow_in = l >> 3;
  const int bswz = (l & 7) ^ brow_in;     // phase-1-verified 8-row swizzle
  const unsigned short* abase = Abf + (long)(m0 + w*16 + brow_in)*K + bswz*8;
  const unsigned short* bbase = Wb  + (long)(n0 + w*16 + brow_in)*K + bswz*8;

#pragma unroll
  for (int q = 0; q < 2; ++q) {
    gld_lds16(abase + (long)q*8*K, As + (w*16 + q*8)*64);
    gld_lds16(bbase + (long)q*8*K, Bs + (w*16 + q*8)*64);
  }
  __syncthreads();
  int cb = 0;
  for (int kt = 0; kt < 24; ++kt) {
    const int nb = cb ^ 1;
    if (kt + 1 < 24) {
      const int k0 = (kt+1) * 64;
#pragma unroll
      for (int q = 0; q < 2; ++q) {
        gld_lds16(abase + (long)q*8*K + k0, As + nb*4096 + (w*16 + q*8)*64);
        gld_lds16(bbase + (long)q*8*K + k0, Bs + nb*4096 + (w*16 + q*8)*64);
      }
    }
#pragma unroll
    for (int h = 0; h < 2; ++h) {
      const int ko = ((g + 4*h) ^ rs) << 3;
      bf16x8 afr[2], bfr[2];
#pragma unroll
      for (int i = 0; i < 2; ++i)
        afr[i] = *reinterpret_cast<const bf16x8*>(As + cb*4096 + (wm*32 + i*16 + r15)*64 + ko);
#pragma unroll
      for (int j = 0; j < 2; ++j)
        bfr[j] = *reinterpret_cast<const bf16x8*>(Bs + cb*4096 + (wn*32 + j*16 + r15)*64 + ko);
#pragma unroll
      for (int i = 0; i < 2; ++i)
#pragma unroll
        for (int j = 0; j < 2; ++j)
          acc[i][j] = mfma16(afr[i], bfr[j], acc[i][j]);
    }
    if (kt + 1 < 24) { __syncthreads(); cb = nb; }
  }
#pragma unroll
  for (int i = 0; i < 2; ++i)
#pragma unroll
    for (int r = 0; r < 4; ++r) {
      int m = m0 + wm*32 + i*16 + g*4 + r;
#pragma unroll
      for (int j = 0; j < 2; ++j) {
        int n = n0 + wn*32 + j*16 + r15;
        float x = acc[i][j][r] + bias[n];
        if (do_tanh) x = fast_tanh(x);
        Cout[(long)m * 512 + n] = x;
      }
    }
}

__global__ __launch_bounds__(256) void k_gemm_small(
    const unsigned short* __restrict__ Abf, const unsigned short* __restrict__ Wb,
    const float* __restrict__ bias, float* __restrict__ Cout, int do_tanh){
  __shared__ __align__(16) unsigned short As[2*64*64];
  __shared__ __align__(16) unsigned short Bs[2*64*64];
  small_gemm_body(Abf, Wb, bias, Cout, do_tanh, blockIdx.x, As, Bs);
}

__global__ __launch_bounds__(256) void k_embed2(
    const unsigned short* __restrict__ h_cat, const unsigned short* __restrict__ W_h_cat,
    const float* __restrict__ b_h, float* __restrict__ h_e,
    const unsigned short* __restrict__ s_cat, const unsigned short* __restrict__ W_s_cat,
    const float* __restrict__ b_s, float* __restrict__ sent_e){
  __shared__ __align__(16) unsigned short As[2*64*64];
  __shared__ __align__(16) unsigned short Bs[2*64*64];
  if (blockIdx.y == 0) small_gemm_body(h_cat, W_h_cat, b_h, h_e, 0, blockIdx.x, As, Bs);
  else                 small_gemm_body(s_cat, W_s_cat, b_s, sent_e, 0, blockIdx.x, As, Bs);
}

extern "C" void kernel_launch(void* const* d_in, const int* in_sizes, int n_in,
                              void* d_out, int out_size, void* d_ws, size_t ws_size,
                              hipStream_t stream){
  (void)in_sizes; (void)n_in; (void)out_size; (void)ws_size;
  const float* h    = (const float*)d_in[0];
  const float* sent = (const float*)d_in[1];
  const float* feats= (const float*)d_in[2];
  const float* W_ae = (const float*)d_in[3];
  const float* b_ae = (const float*)d_in[4];
  const float* W_c  = (const float*)d_in[5];
  const float* b_c  = (const float*)d_in[6];
  const float* W_s  = (const float*)d_in[7];
  const float* b_s  = (const float*)d_in[8];
  const float* W_h  = (const float*)d_in[9];
  const float* b_h  = (const float*)d_in[10];
  const float* W_al = (const float*)d_in[11];
  const float* W_o  = (const float*)d_in[13];
  const float* b_o  = (const float*)d_in[14];
  float* out = (float*)d_out;

  char* p = (char*)d_ws;
  unsigned short* W_ae_bf = (unsigned short*)p; p += (size_t)512*2048*2;
  unsigned short* W_c_bf  = (unsigned short*)p; p += (size_t)512*512*2;
  unsigned short* W_s_cat = (unsigned short*)p; p += (size_t)512*1536*2;
  unsigned short* W_h_cat = (unsigned short*)p; p += (size_t)512*1536*2;
  unsigned short* W_o_cat = (unsigned short*)p; p += (size_t)512*1536*2;
  unsigned short* h_cat   = (unsigned short*)p; p += (size_t)1024*1536*2;
  unsigned short* s_cat   = (unsigned short*)p; p += (size_t)1024*1536*2;
  unsigned short* at_cat  = (unsigned short*)p; p += (size_t)1024*1536*2;
  float* h_e    = (float*)p; p += (size_t)1024*512*4;
  float* sent_e = (float*)p; p += (size_t)1024*512*4;

  k_convert<<<dim3(1024,7), 256, 0, stream>>>(W_ae, W_c, W_s, W_h, W_o, h, sent,
        W_ae_bf, W_c_bf, W_s_cat, W_h_cat, W_o_cat, h_cat, s_cat);
  k_embed2<<<dim3(128,2), 256, 0, stream>>>(h_cat, W_h_cat, b_h, h_e,
                                            s_cat, W_s_cat, b_s, sent_e);
  k_fused<<<1024, 1024, 0, stream>>>(feats, W_ae_bf, b_ae, W_c_bf, b_c,
                                     h_e, W_al, sent_e, sent, h, at_cat);
  k_gemm_small<<<128, 256, 0, stream>>>(at_cat, W_o_cat, b_o, out, 1);
}